// Round 19
// baseline (172.198 us; speedup 1.0000x reference)
//
#include <hip/hip_runtime.h>
#include <hip/hip_bf16.h>
#include <math.h>

#define B_ 4
#define N_ 32768
#define CIN 6
#define C_ 64
#define R_ 16
#define S_ 4096

typedef __attribute__((ext_vector_type(8))) __bf16 bf16x8;
typedef __attribute__((ext_vector_type(8))) short short8;
typedef __attribute__((ext_vector_type(4))) short s16x4;
typedef __attribute__((ext_vector_type(4))) float f32x4;

#define MFMA16(a, b, c) __builtin_amdgcn_mfma_f32_16x16x32_bf16((a), (b), (c), 0, 0, 0)

__device__ inline f32x4 zero4() {
    f32x4 z;
    z[0] = 0.f; z[1] = 0.f; z[2] = 0.f; z[3] = 0.f;
    return z;
}

__device__ inline unsigned short f2bf(float f) {
    unsigned u = __builtin_bit_cast(unsigned, f);
    u += 0x7fffu + ((u >> 16) & 1u);          // RNE
    return (unsigned short)(u >> 16);
}

__device__ inline float bf2f(unsigned short s) {
    unsigned u = ((unsigned)s) << 16;
    return __builtin_bit_cast(float, u);
}

__device__ inline short8 pack8(float4 a, float4 b) {
    short8 r;
    r[0] = (short)f2bf(a.x); r[1] = (short)f2bf(a.y); r[2] = (short)f2bf(a.z); r[3] = (short)f2bf(a.w);
    r[4] = (short)f2bf(b.x); r[5] = (short)f2bf(b.y); r[6] = (short)f2bf(b.z); r[7] = (short)f2bf(b.w);
    return r;
}

__device__ inline bf16x8 pack8b(float4 a, float4 b) {
    return __builtin_bit_cast(bf16x8, pack8(a, b));
}

// ---------------- K1a: per-block partial LDS histograms (no global atomics) ----------------
__global__ __launch_bounds__(1024) void k_vox_part(const float* __restrict__ coords,
                                                   const float* __restrict__ feats,
                                                   float* __restrict__ part) {
    __shared__ float hist[7 * S_];             // 114688 B
    int bid = blockIdx.x;                      // 64: b(4) x p(16)
    int b = bid >> 4, p = bid & 15;
    int tid = threadIdx.x;
    for (int i = tid; i < 7 * S_; i += 1024) hist[i] = 0.f;
    __syncthreads();
    const float* cb = coords + (size_t)b * 3 * N_;
    const float* fb = feats + (size_t)b * CIN * N_;
#pragma unroll
    for (int it = 0; it < 2; ++it) {
        int n = p * 2048 + it * 1024 + tid;
        float x = cb[n], y = cb[N_ + n], z = cb[2 * N_ + n];
        int vx = min(max((int)floorf(x * R_), 0), R_ - 1);
        int vy = min(max((int)floorf(y * R_), 0), R_ - 1);
        int vz = min(max((int)floorf(z * R_), 0), R_ - 1);
        int cell = (vx * R_ + vy) * R_ + vz;
#pragma unroll
        for (int f = 0; f < CIN; f++) atomicAdd(&hist[f * S_ + cell], fb[f * N_ + n]);
        atomicAdd(&hist[6 * S_ + cell], 1.0f);
    }
    __syncthreads();
    float* dst = part + (size_t)bid * (7 * S_);
    for (int i = tid; i < 7 * S_; i += 1024) dst[i] = hist[i];
}

// ---------------- K1b: fold 16 partials -> vsum, cnt ----------------
__global__ __launch_bounds__(256) void k_vox_reduce(const float* __restrict__ part,
                                                    float* __restrict__ vsum, float* __restrict__ cnt) {
    int idx = blockIdx.x * 256 + threadIdx.x;  // 4 * 28672 = 114688 threads
    int b = idx / (7 * S_);
    int r = idx - b * (7 * S_);
    const float* pb = part + (size_t)b * 16 * (7 * S_) + r;
    float s = 0.f;
#pragma unroll
    for (int p = 0; p < 16; p++) s += pb[(size_t)p * (7 * S_)];
    if (r < CIN * S_) vsum[(size_t)b * CIN * S_ + r] = s;
    else cnt[b * S_ + (r - CIN * S_)] = s;
}

// ---------------- K2: conv + fused mean-division -> voxT f32 [b][s][64] ----------------
__global__ __launch_bounds__(256) void k_conv2(const float* __restrict__ vsum, const float* __restrict__ cnt,
                                               const float* __restrict__ w, const float* __restrict__ bias,
                                               float* __restrict__ voxT) {
    __shared__ float msl[3][CIN][256];
    __shared__ float wl[8 * 162];
    int bid = blockIdx.x;                 // b(4) x x(16) x og(8) = 512
    int b = bid >> 7;
    int x = (bid >> 3) & 15;
    int o0 = (bid & 7) * 8;
    int tid = threadIdx.x;
    for (int i = tid; i < 8 * 162; i += 256) wl[i] = w[o0 * 162 + i];
#pragma unroll
    for (int sl = 0; sl < 3; sl++) {
        int xx = x - 1 + sl;
        if (xx >= 0 && xx < 16) {
            float c = cnt[b * S_ + xx * 256 + tid];
            float invc = 1.f / fmaxf(c, 1.f);
#pragma unroll
            for (int i = 0; i < CIN; i++)
                msl[sl][i][tid] = vsum[((size_t)b * CIN + i) * S_ + xx * 256 + tid] * invc;
        } else {
#pragma unroll
            for (int i = 0; i < CIN; i++) msl[sl][i][tid] = 0.f;
        }
    }
    __syncthreads();
    int y = tid >> 4, z = tid & 15;
    float acc[8];
#pragma unroll
    for (int oj = 0; oj < 8; oj++) acc[oj] = bias[o0 + oj];
#pragma unroll
    for (int dx = 0; dx < 3; dx++) {
#pragma unroll
        for (int dy = 0; dy < 3; dy++) {
            int yy = y + dy - 1;
            if ((unsigned)yy >= 16u) continue;
#pragma unroll
            for (int dz = 0; dz < 3; dz++) {
                int zz = z + dz - 1;
                if ((unsigned)zz >= 16u) continue;
                int idx = yy * 16 + zz;
#pragma unroll
                for (int i = 0; i < CIN; i++) {
                    float m = msl[dx][i][idx];
                    int wb = i * 27 + dx * 9 + dy * 3 + dz;
#pragma unroll
                    for (int oj = 0; oj < 8; oj++) acc[oj] += wl[oj * 162 + wb] * m;
                }
            }
        }
    }
    int cell = x * 256 + tid;
    float* dst = voxT + ((size_t)b * S_ + cell) * 64 + o0;
    *(float4*)dst = make_float4(fmaxf(acc[0], 0.f), fmaxf(acc[1], 0.f), fmaxf(acc[2], 0.f), fmaxf(acc[3], 0.f));
    *(float4*)(dst + 4) = make_float4(fmaxf(acc[4], 0.f), fmaxf(acc[5], 0.f), fmaxf(acc[6], 0.f), fmaxf(acc[7], 0.f));
}

// ---------------- K3: qkv via MFMA -> qT,kT [s][64]; vT [c][t] ----------------
__global__ __launch_bounds__(256) void k_qkv4(const float* __restrict__ voxT,
                                              const float* __restrict__ wq, const float* __restrict__ wk,
                                              const float* __restrict__ wv,
                                              unsigned short* __restrict__ qT, unsigned short* __restrict__ kT,
                                              unsigned short* __restrict__ vT) {
    int bid = blockIdx.x;                 // 256: b(4) x chunk(64)
    int b = bid >> 6;
    int srow = (bid & 63) * 64 + (threadIdx.x >> 6) * 16;   // 16 rows per wave
    int lane = threadIdx.x & 63;
    int lo = lane & 15, hi = lane >> 4;

    const float* xr = voxT + ((size_t)b * S_ + srow + lo) * 64 + hi * 8;
    bf16x8 a0 = pack8b(*(const float4*)xr, *(const float4*)(xr + 4));
    bf16x8 a1 = pack8b(*(const float4*)(xr + 32), *(const float4*)(xr + 36));

#pragma unroll
    for (int m = 0; m < 3; m++) {
        const float* wp = (m == 0) ? wq : (m == 1) ? wk : wv;
#pragma unroll
        for (int oc = 0; oc < 4; oc++) {
            const float* wr = wp + (oc * 16 + lo) * 64 + hi * 8;
            bf16x8 b0 = pack8b(*(const float4*)wr, *(const float4*)(wr + 4));
            bf16x8 b1 = pack8b(*(const float4*)(wr + 32), *(const float4*)(wr + 36));
            f32x4 acc = zero4();
            acc = MFMA16(a0, b0, acc);
            acc = MFMA16(a1, b1, acc);
            if (m < 2) {
                unsigned short* dst = ((m == 0) ? qT : kT) + ((size_t)b * S_ + srow + hi * 4) * 64 + oc * 16 + lo;
#pragma unroll
                for (int j = 0; j < 4; j++) dst[(size_t)j * 64] = f2bf(acc[j]);
            } else {
                s16x4 pk;
#pragma unroll
                for (int j = 0; j < 4; j++) pk[j] = (short)f2bf(acc[j]);
                *(s16x4*)(vT + ((size_t)b * 64 + oc * 16 + lo) * S_ + srow + hi * 4) = pk;
            }
        }
    }
}

// ---------------- K4: attn — shared LDS K/V tiles, T14 staging, waves own disjoint 16-row q-tiles ----------------
__global__ __launch_bounds__(256) void k_attn11(const unsigned short* __restrict__ qT,
                                                const unsigned short* __restrict__ kT,
                                                const unsigned short* __restrict__ vT,
                                                float* __restrict__ Opart, float* __restrict__ lpart) {
    __shared__ __align__(16) char Kl[8192];     // 64 t-rows x 128B, XOR-swizzled slots
    __shared__ __align__(16) char Vl[8192];     // 64 c-rows x 128B, XOR-swizzled slots
    __shared__ __align__(16) char PsB[8192];    // per-wave 2KB P buffer
    int bid = blockIdx.x;                       // 512: b(4) x qt(64) x half(2)
    int b = bid >> 7;
    int qt = (bid >> 1) & 63;
    int half = bid & 1;
    int sq0 = qt * 64;
    int tid = threadIdx.x;
    int w = tid >> 6, lane = tid & 63;
    int lo = lane & 15, hi = lane >> 4;
    char* Ps = PsB + w * 2048;

    const unsigned short* qb = qT + ((size_t)b * S_ + sq0 + w * 16) * 64;
    bf16x8 qf0 = __builtin_bit_cast(bf16x8, *(const short8*)(qb + lo * 64 + hi * 8));
    bf16x8 qf1 = __builtin_bit_cast(bf16x8, *(const short8*)(qb + lo * 64 + hi * 8 + 32));

    f32x4 O[4];
    float l[4];
#pragma unroll
    for (int cc = 0; cc < 4; cc++) O[cc] = zero4();
#pragma unroll
    for (int j = 0; j < 4; j++) l[j] = 0.f;

    const char* kTb = (const char*)(kT + (size_t)b * S_ * 64);   // t-row = 128B
    const char* vTb = (const char*)(vT + (size_t)b * 64 * S_);   // c-row = 8192B
    int tbase = half * 2048;

    int swz = ((tid >> 3) & 7) << 4;
    int x0 = tid * 16;
    int vrow = tid >> 3, vslot16 = (tid & 7) * 16;

    short8 g0, g1, g2, g3;
    {
        const char* ktile = kTb + (size_t)tbase * 128;
        g0 = *(const short8*)(ktile + x0);
        g1 = *(const short8*)(ktile + x0 + 4096);
        const char* vt0 = vTb + (size_t)tbase * 2;
        g2 = *(const short8*)(vt0 + (size_t)vrow * 8192 + vslot16);
        g3 = *(const short8*)(vt0 + (size_t)(vrow + 32) * 8192 + vslot16);
    }

    for (int it = 0; it < 32; ++it) {
        __syncthreads();
        *(short8*)(Kl + (x0 ^ swz)) = g0;
        *(short8*)(Kl + ((x0 + 4096) ^ swz)) = g1;
        *(short8*)(Vl + (x0 ^ swz)) = g2;
        *(short8*)(Vl + ((x0 + 4096) ^ swz)) = g3;
        __syncthreads();
        if (it + 1 < 32) {
            int t0n = tbase + (it + 1) * 64;
            const char* ktile = kTb + (size_t)t0n * 128;
            g0 = *(const short8*)(ktile + x0);
            g1 = *(const short8*)(ktile + x0 + 4096);
            const char* vtn = vTb + (size_t)t0n * 2;
            g2 = *(const short8*)(vtn + (size_t)vrow * 8192 + vslot16);
            g3 = *(const short8*)(vtn + (size_t)(vrow + 32) * 8192 + vslot16);
        }
#pragma unroll
        for (int ct = 0; ct < 4; ct++) {
            int t = ct * 16 + lo;
            int tswz = (t & 7) << 4;
            bf16x8 kf0 = __builtin_bit_cast(bf16x8, *(const short8*)(Kl + (t * 128 + ((hi * 16) ^ tswz))));
            bf16x8 kf1 = __builtin_bit_cast(bf16x8, *(const short8*)(Kl + (t * 128 + ((64 + hi * 16) ^ tswz))));
            f32x4 z = zero4();
            z = MFMA16(qf0, kf0, z);
            f32x4 Sacc = MFMA16(qf1, kf1, z);
#pragma unroll
            for (int j = 0; j < 4; j++) {
                float p = __expf(Sacc[j] * 0.125f);
                l[j] += p;
                int r = hi * 4 + j;
                int pswz = (r & 7) << 4;
                *(unsigned short*)(Ps + ((r * 128 + t * 2) ^ pswz)) = f2bf(p);
            }
        }
        int rswz = (lo & 7) << 4;
        bf16x8 pa0 = __builtin_bit_cast(bf16x8, *(const short8*)(Ps + ((lo * 128 + hi * 16) ^ rswz)));
        bf16x8 pa1 = __builtin_bit_cast(bf16x8, *(const short8*)(Ps + ((lo * 128 + 64 + hi * 16) ^ rswz)));
#pragma unroll
        for (int cc = 0; cc < 4; cc++) {
            int c = cc * 16 + lo;
            int cswz = (c & 7) << 4;
            bf16x8 vf0 = __builtin_bit_cast(bf16x8, *(const short8*)(Vl + (c * 128 + ((hi * 16) ^ cswz))));
            bf16x8 vf1 = __builtin_bit_cast(bf16x8, *(const short8*)(Vl + (c * 128 + ((64 + hi * 16) ^ cswz))));
            O[cc] = MFMA16(pa0, vf0, O[cc]);
            O[cc] = MFMA16(pa1, vf1, O[cc]);
        }
    }

    float* ob = Opart + ((size_t)(half * B_ + b) * S_ + sq0 + w * 16) * 64;
#pragma unroll
    for (int cc = 0; cc < 4; cc++)
#pragma unroll
        for (int j = 0; j < 4; j++)
            ob[(size_t)(hi * 4 + j) * 64 + cc * 16 + lo] = O[cc][j];
#pragma unroll
    for (int j = 0; j < 4; j++) {
        float s = l[j];
        s += __shfl_xor(s, 1);
        s += __shfl_xor(s, 2);
        s += __shfl_xor(s, 4);
        s += __shfl_xor(s, 8);
        if (lo == 0)
            lpart[(size_t)(half * B_ + b) * S_ + sq0 + w * 16 + hi * 4 + j] = s;
    }
}

// ---------------- K5: combine(2 halves) + Wo MFMA + residual + SE-mean -> xattT bf16 ----------------
__global__ __launch_bounds__(256) void k_wo_mfma(const float* __restrict__ Opart,
                                                 const float* __restrict__ lpart,
                                                 const float* __restrict__ wo,
                                                 const float* __restrict__ voxT,
                                                 unsigned short* __restrict__ xattT,
                                                 float* __restrict__ semean) {
    __shared__ float sem[64];
    int tid = threadIdx.x;
    if (tid < 64) sem[tid] = 0.f;
    __syncthreads();
    int wid = tid >> 6, lane = tid & 63;
    int lo = lane & 15, hi = lane >> 4;
    int r0 = blockIdx.x * 64 + wid * 16;               // global row (b*S + s)
    int bidx = r0 >> 12;
    int row = r0 + lo;
    const int BS = B_ * S_;

    float L = lpart[row] + lpart[BS + row];
    float inv = 1.f / L;
    float4 q0 = make_float4(0.f, 0.f, 0.f, 0.f), q1 = q0, q2 = q0, q3 = q0;
#pragma unroll
    for (int sp = 0; sp < 2; sp++) {
        const float* orow = Opart + ((size_t)sp * BS + row) * 64 + hi * 8;
        float4 t0 = *(const float4*)(orow);
        float4 t1 = *(const float4*)(orow + 4);
        float4 t2 = *(const float4*)(orow + 32);
        float4 t3 = *(const float4*)(orow + 36);
        q0.x += t0.x; q0.y += t0.y; q0.z += t0.z; q0.w += t0.w;
        q1.x += t1.x; q1.y += t1.y; q1.z += t1.z; q1.w += t1.w;
        q2.x += t2.x; q2.y += t2.y; q2.z += t2.z; q2.w += t2.w;
        q3.x += t3.x; q3.y += t3.y; q3.z += t3.z; q3.w += t3.w;
    }
    q0.x *= inv; q0.y *= inv; q0.z *= inv; q0.w *= inv;
    q1.x *= inv; q1.y *= inv; q1.z *= inv; q1.w *= inv;
    q2.x *= inv; q2.y *= inv; q2.z *= inv; q2.w *= inv;
    q3.x *= inv; q3.y *= inv; q3.z *= inv; q3.w *= inv;
    bf16x8 a0 = pack8b(q0, q1);
    bf16x8 a1 = pack8b(q2, q3);

    float colsum[4];
#pragma unroll
    for (int cc = 0; cc < 4; cc++) {
        int o = cc * 16 + lo;
        float4 f0 = *(const float4*)(wo + o * 64 + hi * 8);
        float4 f1 = *(const float4*)(wo + o * 64 + hi * 8 + 4);
        bf16x8 b0 = pack8b(f0, f1);
        float4 f2 = *(const float4*)(wo + o * 64 + 32 + hi * 8);
        float4 f3 = *(const float4*)(wo + o * 64 + 32 + hi * 8 + 4);
        bf16x8 b1 = pack8b(f2, f3);
        f32x4 acc = zero4();
        acc = MFMA16(a0, b0, acc);
        acc = MFMA16(a1, b1, acc);
        float cs = 0.f;
#pragma unroll
        for (int j = 0; j < 4; j++) {
            size_t idx = (size_t)(r0 + hi * 4 + j) * 64 + o;
            float xn = acc[j] + voxT[idx];
            xattT[idx] = f2bf(xn);
            cs += xn;
        }
        cs += __shfl_xor(cs, 16);
        cs += __shfl_xor(cs, 32);
        colsum[cc] = cs;
    }
    if (hi == 0) {
#pragma unroll
        for (int cc = 0; cc < 4; cc++) atomicAdd(&sem[cc * 16 + lo], colsum[cc]);
    }
    __syncthreads();
    if (tid < 64) atomicAdd(&semean[bidx * 64 + tid], sem[tid]);
}

// ---------------- K8: SE gate + devoxelize (bf16 gather) + point MLP + MFMA classifier ----------------
__global__ __launch_bounds__(256) void k_point(const float* __restrict__ coords, const float* __restrict__ feats,
                                               const unsigned short* __restrict__ xt, const float* __restrict__ semean,
                                               const float* __restrict__ sw1, const float* __restrict__ sb1,
                                               const float* __restrict__ sw2, const float* __restrict__ sb2,
                                               const float* __restrict__ pw,
                                               const float* __restrict__ pb, const float* __restrict__ w1,
                                               const float* __restrict__ b1, const float* __restrict__ w2,
                                               const float* __restrict__ b2, float* __restrict__ out) {
    __shared__ unsigned short fl[256 * 64];    // 32KB fused bf16, XOR-swizzled rows
    __shared__ float pwl[64 * 6];
    __shared__ float pbl[64];
    __shared__ float b1l[128];
    __shared__ float w2l[3 * 128];
    __shared__ float b2l[3];
    __shared__ float gl[64];
    __shared__ float sml[64];
    __shared__ float hh[8];
    int tid = threadIdx.x;
    int gidx0 = blockIdx.x * 256;
    int b = gidx0 >> 15, n0 = gidx0 & (N_ - 1);
    int n = n0 + tid;
    for (int i = tid; i < 384; i += 256) { pwl[i] = pw[i]; w2l[i] = w2[i]; }
    if (tid < 128) b1l[tid] = b1[tid];
    if (tid < 64) { pbl[tid] = pb[tid]; sml[tid] = semean[b * 64 + tid] * (1.0f / S_); }
    if (tid < 3) b2l[tid] = b2[tid];
    __syncthreads();
    if (tid < 8) {
        float a = sb1[tid];
#pragma unroll
        for (int i = 0; i < 64; i++) a += sw1[tid * 64 + i] * sml[i];
        hh[tid] = fmaxf(a, 0.f);
    }
    __syncthreads();
    if (tid < 64) {
        float g = sb2[tid];
#pragma unroll
        for (int j = 0; j < 8; j++) g += sw2[tid * 8 + j] * hh[j];
        gl[tid] = 1.f / (1.f + __expf(-g));
    }
    __syncthreads();

    const float* cb = coords + (size_t)b * 3 * N_;
    float px = fminf(fmaxf(cb[n] * R_ - 0.5f, 0.f), 15.f);
    float py = fminf(fmaxf(cb[N_ + n] * R_ - 0.5f, 0.f), 15.f);
    float pz = fminf(fmaxf(cb[2 * N_ + n] * R_ - 0.5f, 0.f), 15.f);
    int x0 = (int)floorf(px); float wx = px - x0; int x1 = min(x0 + 1, 15);
    int y0 = (int)floorf(py); float wy = py - y0; int y1 = min(y0 + 1, 15);
    int z0 = (int)floorf(pz); float wz = pz - z0; int z1 = min(z0 + 1, 15);
    float fused[64];
#pragma unroll
    for (int c = 0; c < 64; c++) fused[c] = 0.f;
    const unsigned short* xb = xt + (size_t)b * S_ * 64;
#pragma unroll
    for (int dx = 0; dx < 2; dx++) {
#pragma unroll
        for (int dy = 0; dy < 2; dy++) {
#pragma unroll
            for (int dz = 0; dz < 2; dz++) {
                int xi = dx ? x1 : x0, yi = dy ? y1 : y0, zi = dz ? z1 : z0;
                float wgt = (dx ? wx : 1.f - wx) * (dy ? wy : 1.f - wy) * (dz ? wz : 1.f - wz);
                const short8* g = (const short8*)(xb + (size_t)((xi * 16 + yi) * 16 + zi) * 64);
#pragma unroll
                for (int c8 = 0; c8 < 8; c8++) {
                    short8 gv = g[c8];
#pragma unroll
                    for (int i = 0; i < 8; i++)
                        fused[c8 * 8 + i] += wgt * bf2f((unsigned short)gv[i]);
                }
            }
        }
    }
    float fv[6];
#pragma unroll
    for (int i = 0; i < 6; i++) fv[i] = feats[((size_t)b * 6 + i) * N_ + n];
#pragma unroll
    for (int c = 0; c < 64; c++) {
        float pt = pbl[c];
#pragma unroll
        for (int i = 0; i < 6; i++) pt += pwl[c * 6 + i] * fv[i];
        pt = fmaxf(pt, 0.f);
        fused[c] = fmaxf(fused[c] * gl[c] + pt, 0.f);
    }
#pragma unroll
    for (int ch = 0; ch < 8; ch++) {
        short8 v;
#pragma unroll
        for (int i = 0; i < 8; i++) v[i] = (short)f2bf(fused[ch * 8 + i]);
        int byte = tid * 128 + ch * 16;
        *(short8*)((char*)fl + (byte ^ ((tid & 7) << 4))) = v;
    }
    __syncthreads();

    int wv = tid >> 6, lane = tid & 63;
    int lo = lane & 15, hi = lane >> 4;
#pragma unroll
    for (int g = 0; g < 4; g++) {
        int row = wv * 64 + g * 16 + lo;
        int swz = (row & 7) << 4;
        bf16x8 a0 = __builtin_bit_cast(bf16x8, *(const short8*)((char*)fl + ((row * 128 + hi * 16) ^ swz)));
        bf16x8 a1 = __builtin_bit_cast(bf16x8, *(const short8*)((char*)fl + ((row * 128 + 64 + hi * 16) ^ swz)));
        float s0[4] = {0.f, 0.f, 0.f, 0.f};
        float s1[4] = {0.f, 0.f, 0.f, 0.f};
        float s2[4] = {0.f, 0.f, 0.f, 0.f};
#pragma unroll
        for (int th = 0; th < 8; th++) {
            // B-frags loaded per-iteration (L2-hot w1) to keep register peak low
            const float* wr0 = w1 + (th * 16 + lo) * 64 + hi * 8;
            bf16x8 bw0 = pack8b(*(const float4*)wr0, *(const float4*)(wr0 + 4));
            const float* wr1 = wr0 + 32;
            bf16x8 bw1 = pack8b(*(const float4*)wr1, *(const float4*)(wr1 + 4));
            f32x4 acc = zero4();
            acc = MFMA16(a0, bw0, acc);
            acc = MFMA16(a1, bw1, acc);
            int hidx = th * 16 + lo;
            float w2o0 = w2l[hidx];
            float w2o1 = w2l[128 + hidx];
            float w2o2 = w2l[256 + hidx];
            float bias = b1l[hidx];
#pragma unroll
            for (int j = 0; j < 4; j++) {
                float hj = fmaxf(acc[j] + bias, 0.f);
                s0[j] += hj * w2o0;
                s1[j] += hj * w2o1;
                s2[j] += hj * w2o2;
            }
        }
#pragma unroll
        for (int j = 0; j < 4; j++) {
            s0[j] += __shfl_xor(s0[j], 1); s0[j] += __shfl_xor(s0[j], 2);
            s0[j] += __shfl_xor(s0[j], 4); s0[j] += __shfl_xor(s0[j], 8);
            s1[j] += __shfl_xor(s1[j], 1); s1[j] += __shfl_xor(s1[j], 2);
            s1[j] += __shfl_xor(s1[j], 4); s1[j] += __shfl_xor(s1[j], 8);
            s2[j] += __shfl_xor(s2[j], 1); s2[j] += __shfl_xor(s2[j], 2);
            s2[j] += __shfl_xor(s2[j], 4); s2[j] += __shfl_xor(s2[j], 8);
        }
        int nbase = n0 + wv * 64 + g * 16 + hi * 4;
        if (lo == 0) {
            float4 o4 = make_float4(s0[0] + b2l[0], s0[1] + b2l[0], s0[2] + b2l[0], s0[3] + b2l[0]);
            *(float4*)(out + ((size_t)b * 3 + 0) * N_ + nbase) = o4;
        } else if (lo == 1) {
            float4 o4 = make_float4(s1[0] + b2l[1], s1[1] + b2l[1], s1[2] + b2l[1], s1[3] + b2l[1]);
            *(float4*)(out + ((size_t)b * 3 + 1) * N_ + nbase) = o4;
        } else if (lo == 2) {
            float4 o4 = make_float4(s2[0] + b2l[2], s2[1] + b2l[2], s2[2] + b2l[2], s2[3] + b2l[2]);
            *(float4*)(out + ((size_t)b * 3 + 2) * N_ + nbase) = o4;
        }
    }
}

extern "C" void kernel_launch(void* const* d_in, const int* in_sizes, int n_in,
                              void* d_out, int out_size, void* d_ws, size_t ws_size,
                              hipStream_t stream) {
    const float* coords  = (const float*)d_in[0];
    const float* feats   = (const float*)d_in[1];
    const float* conv_w  = (const float*)d_in[2];
    const float* conv_b  = (const float*)d_in[3];
    const float* wq      = (const float*)d_in[4];
    const float* wk      = (const float*)d_in[5];
    const float* wv      = (const float*)d_in[6];
    const float* wo      = (const float*)d_in[7];
    const float* se_w1   = (const float*)d_in[8];
    const float* se_b1   = (const float*)d_in[9];
    const float* se_w2   = (const float*)d_in[10];
    const float* se_b2   = (const float*)d_in[11];
    const float* point_w = (const float*)d_in[12];
    const float* point_b = (const float*)d_in[13];
    const float* cls_w1  = (const float*)d_in[14];
    const float* cls_b1  = (const float*)d_in[15];
    const float* cls_w2  = (const float*)d_in[16];
    const float* cls_b2  = (const float*)d_in[17];

    float* ws = (float*)d_ws;
    float* vsum   = ws;                        // 98304
    float* cnt    = ws + 98304;                // 16384
    float* semean = ws + 114688;               // 256
    float* vox    = ws + 115200;               // region reused as xattT (bf16)
    float* voxT   = vox + 1048576;             // f32 [b][s][64]: conv2 -> qkv4 + wo residual
    unsigned short* qT = (unsigned short*)(voxT + 1048576);
    unsigned short* kT = qT + 1048576;
    unsigned short* vT = kT + 1048576;
    float* Opart  = (float*)(vT + 1048576);    // 2097152 f32: vox partials, then attn partials
    float* lpart  = Opart + 2097152;           // 32768
    unsigned short* xattT = (unsigned short*)vox;   // bf16 [b][s][64]

    hipMemsetAsync(semean, 0, 256 * sizeof(float), stream);   // semean only (atomic accum)
    k_vox_part<<<64, 1024, 0, stream>>>(coords, feats, Opart);
    k_vox_reduce<<<448, 256, 0, stream>>>(Opart, vsum, cnt);
    k_conv2<<<512, 256, 0, stream>>>(vsum, cnt, conv_w, conv_b, voxT);
    k_qkv4<<<256, 256, 0, stream>>>(voxT, wq, wk, wv, qT, kT, vT);
    k_attn11<<<512, 256, 0, stream>>>(qT, kT, vT, Opart, lpart);
    k_wo_mfma<<<256, 256, 0, stream>>>(Opart, lpart, wo, voxT, xattT, semean);
    k_point<<<512, 256, 0, stream>>>(coords, feats, xattT, semean,
                                     se_w1, se_b1, se_w2, se_b2, point_w, point_b,
                                     cls_w1, cls_b1, cls_w2, cls_b2, (float*)d_out);
}

// Round 20
// 156.521 us; speedup vs baseline: 1.1002x; 1.1002x over previous
//
#include <hip/hip_runtime.h>
#include <hip/hip_bf16.h>
#include <math.h>

#define B_ 4
#define N_ 32768
#define CIN 6
#define C_ 64
#define R_ 16
#define S_ 4096

typedef __attribute__((ext_vector_type(8))) __bf16 bf16x8;
typedef __attribute__((ext_vector_type(8))) short short8;
typedef __attribute__((ext_vector_type(4))) short s16x4;
typedef __attribute__((ext_vector_type(4))) float f32x4;

#define MFMA16(a, b, c) __builtin_amdgcn_mfma_f32_16x16x32_bf16((a), (b), (c), 0, 0, 0)

__device__ inline f32x4 zero4() {
    f32x4 z;
    z[0] = 0.f; z[1] = 0.f; z[2] = 0.f; z[3] = 0.f;
    return z;
}

__device__ inline unsigned short f2bf(float f) {
    unsigned u = __builtin_bit_cast(unsigned, f);
    u += 0x7fffu + ((u >> 16) & 1u);          // RNE
    return (unsigned short)(u >> 16);
}

__device__ inline float bf2f(unsigned short s) {
    unsigned u = ((unsigned)s) << 16;
    return __builtin_bit_cast(float, u);
}

__device__ inline short8 pack8(float4 a, float4 b) {
    short8 r;
    r[0] = (short)f2bf(a.x); r[1] = (short)f2bf(a.y); r[2] = (short)f2bf(a.z); r[3] = (short)f2bf(a.w);
    r[4] = (short)f2bf(b.x); r[5] = (short)f2bf(b.y); r[6] = (short)f2bf(b.z); r[7] = (short)f2bf(b.w);
    return r;
}

__device__ inline bf16x8 pack8b(float4 a, float4 b) {
    return __builtin_bit_cast(bf16x8, pack8(a, b));
}

// ---------------- K1a: per-block partial LDS histograms (no global atomics) ----------------
__global__ __launch_bounds__(1024) void k_vox_part(const float* __restrict__ coords,
                                                   const float* __restrict__ feats,
                                                   float* __restrict__ part) {
    __shared__ float hist[7 * S_];             // 114688 B
    int bid = blockIdx.x;                      // 64: b(4) x p(16)
    int b = bid >> 4, p = bid & 15;
    int tid = threadIdx.x;
    for (int i = tid; i < 7 * S_; i += 1024) hist[i] = 0.f;
    __syncthreads();
    const float* cb = coords + (size_t)b * 3 * N_;
    const float* fb = feats + (size_t)b * CIN * N_;
#pragma unroll
    for (int it = 0; it < 2; ++it) {
        int n = p * 2048 + it * 1024 + tid;
        float x = cb[n], y = cb[N_ + n], z = cb[2 * N_ + n];
        int vx = min(max((int)floorf(x * R_), 0), R_ - 1);
        int vy = min(max((int)floorf(y * R_), 0), R_ - 1);
        int vz = min(max((int)floorf(z * R_), 0), R_ - 1);
        int cell = (vx * R_ + vy) * R_ + vz;
#pragma unroll
        for (int f = 0; f < CIN; f++) atomicAdd(&hist[f * S_ + cell], fb[f * N_ + n]);
        atomicAdd(&hist[6 * S_ + cell], 1.0f);
    }
    __syncthreads();
    float* dst = part + (size_t)bid * (7 * S_);
    for (int i = tid; i < 7 * S_; i += 1024) dst[i] = hist[i];
}

// ---------------- K1b: fold 16 partials -> vsum, cnt ----------------
__global__ __launch_bounds__(256) void k_vox_reduce(const float* __restrict__ part,
                                                    float* __restrict__ vsum, float* __restrict__ cnt) {
    int idx = blockIdx.x * 256 + threadIdx.x;  // 4 * 28672 = 114688 threads
    int b = idx / (7 * S_);
    int r = idx - b * (7 * S_);
    const float* pb = part + (size_t)b * 16 * (7 * S_) + r;
    float s = 0.f;
#pragma unroll
    for (int p = 0; p < 16; p++) s += pb[(size_t)p * (7 * S_)];
    if (r < CIN * S_) vsum[(size_t)b * CIN * S_ + r] = s;
    else cnt[b * S_ + (r - CIN * S_)] = s;
}

// ---------------- K2: conv + fused mean-division -> voxT f32 [b][s][64] ----------------
__global__ __launch_bounds__(256) void k_conv2(const float* __restrict__ vsum, const float* __restrict__ cnt,
                                               const float* __restrict__ w, const float* __restrict__ bias,
                                               float* __restrict__ voxT) {
    __shared__ float msl[3][CIN][256];
    __shared__ float wl[8 * 162];
    int bid = blockIdx.x;                 // b(4) x x(16) x og(8) = 512
    int b = bid >> 7;
    int x = (bid >> 3) & 15;
    int o0 = (bid & 7) * 8;
    int tid = threadIdx.x;
    for (int i = tid; i < 8 * 162; i += 256) wl[i] = w[o0 * 162 + i];
#pragma unroll
    for (int sl = 0; sl < 3; sl++) {
        int xx = x - 1 + sl;
        if (xx >= 0 && xx < 16) {
            float c = cnt[b * S_ + xx * 256 + tid];
            float invc = 1.f / fmaxf(c, 1.f);
#pragma unroll
            for (int i = 0; i < CIN; i++)
                msl[sl][i][tid] = vsum[((size_t)b * CIN + i) * S_ + xx * 256 + tid] * invc;
        } else {
#pragma unroll
            for (int i = 0; i < CIN; i++) msl[sl][i][tid] = 0.f;
        }
    }
    __syncthreads();
    int y = tid >> 4, z = tid & 15;
    float acc[8];
#pragma unroll
    for (int oj = 0; oj < 8; oj++) acc[oj] = bias[o0 + oj];
#pragma unroll
    for (int dx = 0; dx < 3; dx++) {
#pragma unroll
        for (int dy = 0; dy < 3; dy++) {
            int yy = y + dy - 1;
            if ((unsigned)yy >= 16u) continue;
#pragma unroll
            for (int dz = 0; dz < 3; dz++) {
                int zz = z + dz - 1;
                if ((unsigned)zz >= 16u) continue;
                int idx = yy * 16 + zz;
#pragma unroll
                for (int i = 0; i < CIN; i++) {
                    float m = msl[dx][i][idx];
                    int wb = i * 27 + dx * 9 + dy * 3 + dz;
#pragma unroll
                    for (int oj = 0; oj < 8; oj++) acc[oj] += wl[oj * 162 + wb] * m;
                }
            }
        }
    }
    int cell = x * 256 + tid;
    float* dst = voxT + ((size_t)b * S_ + cell) * 64 + o0;
    *(float4*)dst = make_float4(fmaxf(acc[0], 0.f), fmaxf(acc[1], 0.f), fmaxf(acc[2], 0.f), fmaxf(acc[3], 0.f));
    *(float4*)(dst + 4) = make_float4(fmaxf(acc[4], 0.f), fmaxf(acc[5], 0.f), fmaxf(acc[6], 0.f), fmaxf(acc[7], 0.f));
}

// ---------------- K3: qkv via MFMA -> qT,kT [s][64]; vT [c][t] ----------------
__global__ __launch_bounds__(256) void k_qkv4(const float* __restrict__ voxT,
                                              const float* __restrict__ wq, const float* __restrict__ wk,
                                              const float* __restrict__ wv,
                                              unsigned short* __restrict__ qT, unsigned short* __restrict__ kT,
                                              unsigned short* __restrict__ vT) {
    int bid = blockIdx.x;                 // 256: b(4) x chunk(64)
    int b = bid >> 6;
    int srow = (bid & 63) * 64 + (threadIdx.x >> 6) * 16;   // 16 rows per wave
    int lane = threadIdx.x & 63;
    int lo = lane & 15, hi = lane >> 4;

    const float* xr = voxT + ((size_t)b * S_ + srow + lo) * 64 + hi * 8;
    bf16x8 a0 = pack8b(*(const float4*)xr, *(const float4*)(xr + 4));
    bf16x8 a1 = pack8b(*(const float4*)(xr + 32), *(const float4*)(xr + 36));

#pragma unroll
    for (int m = 0; m < 3; m++) {
        const float* wp = (m == 0) ? wq : (m == 1) ? wk : wv;
#pragma unroll
        for (int oc = 0; oc < 4; oc++) {
            const float* wr = wp + (oc * 16 + lo) * 64 + hi * 8;
            bf16x8 b0 = pack8b(*(const float4*)wr, *(const float4*)(wr + 4));
            bf16x8 b1 = pack8b(*(const float4*)(wr + 32), *(const float4*)(wr + 36));
            f32x4 acc = zero4();
            acc = MFMA16(a0, b0, acc);
            acc = MFMA16(a1, b1, acc);
            if (m < 2) {
                unsigned short* dst = ((m == 0) ? qT : kT) + ((size_t)b * S_ + srow + hi * 4) * 64 + oc * 16 + lo;
#pragma unroll
                for (int j = 0; j < 4; j++) dst[(size_t)j * 64] = f2bf(acc[j]);
            } else {
                s16x4 pk;
#pragma unroll
                for (int j = 0; j < 4; j++) pk[j] = (short)f2bf(acc[j]);
                *(s16x4*)(vT + ((size_t)b * 64 + oc * 16 + lo) * S_ + srow + hi * 4) = pk;
            }
        }
    }
}

// ---------------- K4: attn — shared LDS K/V tiles, T14 staging, waves own disjoint 16-row q-tiles ----------------
__global__ __launch_bounds__(256) void k_attn11(const unsigned short* __restrict__ qT,
                                                const unsigned short* __restrict__ kT,
                                                const unsigned short* __restrict__ vT,
                                                float* __restrict__ Opart, float* __restrict__ lpart) {
    __shared__ __align__(16) char Kl[8192];     // 64 t-rows x 128B, XOR-swizzled slots
    __shared__ __align__(16) char Vl[8192];     // 64 c-rows x 128B, XOR-swizzled slots
    __shared__ __align__(16) char PsB[8192];    // per-wave 2KB P buffer
    int bid = blockIdx.x;                       // 512: b(4) x qt(64) x half(2)
    int b = bid >> 7;
    int qt = (bid >> 1) & 63;
    int half = bid & 1;
    int sq0 = qt * 64;
    int tid = threadIdx.x;
    int w = tid >> 6, lane = tid & 63;
    int lo = lane & 15, hi = lane >> 4;
    char* Ps = PsB + w * 2048;

    const unsigned short* qb = qT + ((size_t)b * S_ + sq0 + w * 16) * 64;
    bf16x8 qf0 = __builtin_bit_cast(bf16x8, *(const short8*)(qb + lo * 64 + hi * 8));
    bf16x8 qf1 = __builtin_bit_cast(bf16x8, *(const short8*)(qb + lo * 64 + hi * 8 + 32));

    f32x4 O[4];
    float l[4];
#pragma unroll
    for (int cc = 0; cc < 4; cc++) O[cc] = zero4();
#pragma unroll
    for (int j = 0; j < 4; j++) l[j] = 0.f;

    const char* kTb = (const char*)(kT + (size_t)b * S_ * 64);   // t-row = 128B
    const char* vTb = (const char*)(vT + (size_t)b * 64 * S_);   // c-row = 8192B
    int tbase = half * 2048;

    int swz = ((tid >> 3) & 7) << 4;
    int x0 = tid * 16;
    int vrow = tid >> 3, vslot16 = (tid & 7) * 16;

    short8 g0, g1, g2, g3;
    {
        const char* ktile = kTb + (size_t)tbase * 128;
        g0 = *(const short8*)(ktile + x0);
        g1 = *(const short8*)(ktile + x0 + 4096);
        const char* vt0 = vTb + (size_t)tbase * 2;
        g2 = *(const short8*)(vt0 + (size_t)vrow * 8192 + vslot16);
        g3 = *(const short8*)(vt0 + (size_t)(vrow + 32) * 8192 + vslot16);
    }

    for (int it = 0; it < 32; ++it) {
        __syncthreads();
        *(short8*)(Kl + (x0 ^ swz)) = g0;
        *(short8*)(Kl + ((x0 + 4096) ^ swz)) = g1;
        *(short8*)(Vl + (x0 ^ swz)) = g2;
        *(short8*)(Vl + ((x0 + 4096) ^ swz)) = g3;
        __syncthreads();
        if (it + 1 < 32) {
            int t0n = tbase + (it + 1) * 64;
            const char* ktile = kTb + (size_t)t0n * 128;
            g0 = *(const short8*)(ktile + x0);
            g1 = *(const short8*)(ktile + x0 + 4096);
            const char* vtn = vTb + (size_t)t0n * 2;
            g2 = *(const short8*)(vtn + (size_t)vrow * 8192 + vslot16);
            g3 = *(const short8*)(vtn + (size_t)(vrow + 32) * 8192 + vslot16);
        }
#pragma unroll
        for (int ct = 0; ct < 4; ct++) {
            int t = ct * 16 + lo;
            int tswz = (t & 7) << 4;
            bf16x8 kf0 = __builtin_bit_cast(bf16x8, *(const short8*)(Kl + (t * 128 + ((hi * 16) ^ tswz))));
            bf16x8 kf1 = __builtin_bit_cast(bf16x8, *(const short8*)(Kl + (t * 128 + ((64 + hi * 16) ^ tswz))));
            f32x4 z = zero4();
            z = MFMA16(qf0, kf0, z);
            f32x4 Sacc = MFMA16(qf1, kf1, z);
#pragma unroll
            for (int j = 0; j < 4; j++) {
                float p = __expf(Sacc[j] * 0.125f);
                l[j] += p;
                int r = hi * 4 + j;
                int pswz = (r & 7) << 4;
                *(unsigned short*)(Ps + ((r * 128 + t * 2) ^ pswz)) = f2bf(p);
            }
        }
        int rswz = (lo & 7) << 4;
        bf16x8 pa0 = __builtin_bit_cast(bf16x8, *(const short8*)(Ps + ((lo * 128 + hi * 16) ^ rswz)));
        bf16x8 pa1 = __builtin_bit_cast(bf16x8, *(const short8*)(Ps + ((lo * 128 + 64 + hi * 16) ^ rswz)));
#pragma unroll
        for (int cc = 0; cc < 4; cc++) {
            int c = cc * 16 + lo;
            int cswz = (c & 7) << 4;
            bf16x8 vf0 = __builtin_bit_cast(bf16x8, *(const short8*)(Vl + (c * 128 + ((hi * 16) ^ cswz))));
            bf16x8 vf1 = __builtin_bit_cast(bf16x8, *(const short8*)(Vl + (c * 128 + ((64 + hi * 16) ^ cswz))));
            O[cc] = MFMA16(pa0, vf0, O[cc]);
            O[cc] = MFMA16(pa1, vf1, O[cc]);
        }
    }

    float* ob = Opart + ((size_t)(half * B_ + b) * S_ + sq0 + w * 16) * 64;
#pragma unroll
    for (int cc = 0; cc < 4; cc++)
#pragma unroll
        for (int j = 0; j < 4; j++)
            ob[(size_t)(hi * 4 + j) * 64 + cc * 16 + lo] = O[cc][j];
#pragma unroll
    for (int j = 0; j < 4; j++) {
        float s = l[j];
        s += __shfl_xor(s, 1);
        s += __shfl_xor(s, 2);
        s += __shfl_xor(s, 4);
        s += __shfl_xor(s, 8);
        if (lo == 0)
            lpart[(size_t)(half * B_ + b) * S_ + sq0 + w * 16 + hi * 4 + j] = s;
    }
}

// ---------------- K5: combine(2 halves) + Wo MFMA + residual + SE-mean -> xattT bf16 ----------------
__global__ __launch_bounds__(256) void k_wo_mfma(const float* __restrict__ Opart,
                                                 const float* __restrict__ lpart,
                                                 const float* __restrict__ wo,
                                                 const float* __restrict__ voxT,
                                                 unsigned short* __restrict__ xattT,
                                                 float* __restrict__ semean) {
    __shared__ float sem[64];
    int tid = threadIdx.x;
    if (tid < 64) sem[tid] = 0.f;
    __syncthreads();
    int wid = tid >> 6, lane = tid & 63;
    int lo = lane & 15, hi = lane >> 4;
    int r0 = blockIdx.x * 64 + wid * 16;               // global row (b*S + s)
    int bidx = r0 >> 12;
    int row = r0 + lo;
    const int BS = B_ * S_;

    float L = lpart[row] + lpart[BS + row];
    float inv = 1.f / L;
    float4 q0 = make_float4(0.f, 0.f, 0.f, 0.f), q1 = q0, q2 = q0, q3 = q0;
#pragma unroll
    for (int sp = 0; sp < 2; sp++) {
        const float* orow = Opart + ((size_t)sp * BS + row) * 64 + hi * 8;
        float4 t0 = *(const float4*)(orow);
        float4 t1 = *(const float4*)(orow + 4);
        float4 t2 = *(const float4*)(orow + 32);
        float4 t3 = *(const float4*)(orow + 36);
        q0.x += t0.x; q0.y += t0.y; q0.z += t0.z; q0.w += t0.w;
        q1.x += t1.x; q1.y += t1.y; q1.z += t1.z; q1.w += t1.w;
        q2.x += t2.x; q2.y += t2.y; q2.z += t2.z; q2.w += t2.w;
        q3.x += t3.x; q3.y += t3.y; q3.z += t3.z; q3.w += t3.w;
    }
    q0.x *= inv; q0.y *= inv; q0.z *= inv; q0.w *= inv;
    q1.x *= inv; q1.y *= inv; q1.z *= inv; q1.w *= inv;
    q2.x *= inv; q2.y *= inv; q2.z *= inv; q2.w *= inv;
    q3.x *= inv; q3.y *= inv; q3.z *= inv; q3.w *= inv;
    bf16x8 a0 = pack8b(q0, q1);
    bf16x8 a1 = pack8b(q2, q3);

    float colsum[4];
#pragma unroll
    for (int cc = 0; cc < 4; cc++) {
        int o = cc * 16 + lo;
        float4 f0 = *(const float4*)(wo + o * 64 + hi * 8);
        float4 f1 = *(const float4*)(wo + o * 64 + hi * 8 + 4);
        bf16x8 b0 = pack8b(f0, f1);
        float4 f2 = *(const float4*)(wo + o * 64 + 32 + hi * 8);
        float4 f3 = *(const float4*)(wo + o * 64 + 32 + hi * 8 + 4);
        bf16x8 b1 = pack8b(f2, f3);
        f32x4 acc = zero4();
        acc = MFMA16(a0, b0, acc);
        acc = MFMA16(a1, b1, acc);
        float cs = 0.f;
#pragma unroll
        for (int j = 0; j < 4; j++) {
            size_t idx = (size_t)(r0 + hi * 4 + j) * 64 + o;
            float xn = acc[j] + voxT[idx];
            xattT[idx] = f2bf(xn);
            cs += xn;
        }
        cs += __shfl_xor(cs, 16);
        cs += __shfl_xor(cs, 32);
        colsum[cc] = cs;
    }
    if (hi == 0) {
#pragma unroll
        for (int cc = 0; cc < 4; cc++) atomicAdd(&sem[cc * 16 + lo], colsum[cc]);
    }
    __syncthreads();
    if (tid < 64) atomicAdd(&semean[bidx * 64 + tid], sem[tid]);
}

// ---------------- K8: SE gate + devoxelize (bf16 gather) + point MLP + MFMA classifier ----------------
__global__ __launch_bounds__(256) void k_point(const float* __restrict__ coords, const float* __restrict__ feats,
                                               const unsigned short* __restrict__ xt, const float* __restrict__ semean,
                                               const float* __restrict__ sw1, const float* __restrict__ sb1,
                                               const float* __restrict__ sw2, const float* __restrict__ sb2,
                                               const float* __restrict__ pw,
                                               const float* __restrict__ pb, const float* __restrict__ w1,
                                               const float* __restrict__ b1, const float* __restrict__ w2,
                                               const float* __restrict__ b2, float* __restrict__ out) {
    __shared__ unsigned short fl[256 * 64];    // 32KB fused bf16, XOR-swizzled rows
    __shared__ float pwl[64 * 6];
    __shared__ float pbl[64];
    __shared__ float b1l[128];
    __shared__ float w2l[3 * 128];
    __shared__ float b2l[3];
    __shared__ float gl[64];
    __shared__ float sml[64];
    __shared__ float hh[8];
    int tid = threadIdx.x;
    int gidx0 = blockIdx.x * 256;
    int b = gidx0 >> 15, n0 = gidx0 & (N_ - 1);
    int n = n0 + tid;
    for (int i = tid; i < 384; i += 256) { pwl[i] = pw[i]; w2l[i] = w2[i]; }
    if (tid < 128) b1l[tid] = b1[tid];
    if (tid < 64) { pbl[tid] = pb[tid]; sml[tid] = semean[b * 64 + tid] * (1.0f / S_); }
    if (tid < 3) b2l[tid] = b2[tid];
    __syncthreads();
    if (tid < 8) {
        float a = sb1[tid];
#pragma unroll
        for (int i = 0; i < 64; i++) a += sw1[tid * 64 + i] * sml[i];
        hh[tid] = fmaxf(a, 0.f);
    }
    __syncthreads();
    if (tid < 64) {
        float g = sb2[tid];
#pragma unroll
        for (int j = 0; j < 8; j++) g += sw2[tid * 8 + j] * hh[j];
        gl[tid] = 1.f / (1.f + __expf(-g));
    }
    __syncthreads();

    const float* cb = coords + (size_t)b * 3 * N_;
    float px = fminf(fmaxf(cb[n] * R_ - 0.5f, 0.f), 15.f);
    float py = fminf(fmaxf(cb[N_ + n] * R_ - 0.5f, 0.f), 15.f);
    float pz = fminf(fmaxf(cb[2 * N_ + n] * R_ - 0.5f, 0.f), 15.f);
    int x0 = (int)floorf(px); float wx = px - x0; int x1 = min(x0 + 1, 15);
    int y0 = (int)floorf(py); float wy = py - y0; int y1 = min(y0 + 1, 15);
    int z0 = (int)floorf(pz); float wz = pz - z0; int z1 = min(z0 + 1, 15);
    float fused[64];
#pragma unroll
    for (int c = 0; c < 64; c++) fused[c] = 0.f;
    const unsigned short* xb = xt + (size_t)b * S_ * 64;
#pragma unroll
    for (int dx = 0; dx < 2; dx++) {
#pragma unroll
        for (int dy = 0; dy < 2; dy++) {
#pragma unroll
            for (int dz = 0; dz < 2; dz++) {
                int xi = dx ? x1 : x0, yi = dy ? y1 : y0, zi = dz ? z1 : z0;
                float wgt = (dx ? wx : 1.f - wx) * (dy ? wy : 1.f - wy) * (dz ? wz : 1.f - wz);
                const short8* g = (const short8*)(xb + (size_t)((xi * 16 + yi) * 16 + zi) * 64);
#pragma unroll
                for (int c8 = 0; c8 < 8; c8++) {
                    short8 gv = g[c8];
#pragma unroll
                    for (int i = 0; i < 8; i++)
                        fused[c8 * 8 + i] += wgt * bf2f((unsigned short)gv[i]);
                }
            }
        }
    }
    float fv[6];
#pragma unroll
    for (int i = 0; i < 6; i++) fv[i] = feats[((size_t)b * 6 + i) * N_ + n];
#pragma unroll
    for (int c = 0; c < 64; c++) {
        float pt = pbl[c];
#pragma unroll
        for (int i = 0; i < 6; i++) pt += pwl[c * 6 + i] * fv[i];
        pt = fmaxf(pt, 0.f);
        fused[c] = fmaxf(fused[c] * gl[c] + pt, 0.f);
    }
#pragma unroll
    for (int ch = 0; ch < 8; ch++) {
        short8 v;
#pragma unroll
        for (int i = 0; i < 8; i++) v[i] = (short)f2bf(fused[ch * 8 + i]);
        int byte = tid * 128 + ch * 16;
        *(short8*)((char*)fl + (byte ^ ((tid & 7) << 4))) = v;
    }
    __syncthreads();

    int wv = tid >> 6, lane = tid & 63;
    int lo = lane & 15, hi = lane >> 4;
    bf16x8 bw[16];
#pragma unroll
    for (int th = 0; th < 8; th++) {
#pragma unroll
        for (int kf = 0; kf < 2; kf++) {
            const float* wr = w1 + (th * 16 + lo) * 64 + kf * 32 + hi * 8;
            bw[th * 2 + kf] = pack8b(*(const float4*)wr, *(const float4*)(wr + 4));
        }
    }
#pragma unroll
    for (int g = 0; g < 4; g++) {
        int row = wv * 64 + g * 16 + lo;
        int swz = (row & 7) << 4;
        bf16x8 a0 = __builtin_bit_cast(bf16x8, *(const short8*)((char*)fl + ((row * 128 + hi * 16) ^ swz)));
        bf16x8 a1 = __builtin_bit_cast(bf16x8, *(const short8*)((char*)fl + ((row * 128 + 64 + hi * 16) ^ swz)));
        f32x4 acc[8];
#pragma unroll
        for (int th = 0; th < 8; th++) {
            acc[th] = zero4();
            acc[th] = MFMA16(a0, bw[th * 2], acc[th]);
            acc[th] = MFMA16(a1, bw[th * 2 + 1], acc[th]);
        }
        float s0[4] = {0.f, 0.f, 0.f, 0.f};
        float s1[4] = {0.f, 0.f, 0.f, 0.f};
        float s2[4] = {0.f, 0.f, 0.f, 0.f};
#pragma unroll
        for (int th = 0; th < 8; th++) {
            int hidx = th * 16 + lo;
            float w2o0 = w2l[hidx];
            float w2o1 = w2l[128 + hidx];
            float w2o2 = w2l[256 + hidx];
            float bias = b1l[hidx];
#pragma unroll
            for (int j = 0; j < 4; j++) {
                float hj = fmaxf(acc[th][j] + bias, 0.f);
                s0[j] += hj * w2o0;
                s1[j] += hj * w2o1;
                s2[j] += hj * w2o2;
            }
        }
#pragma unroll
        for (int j = 0; j < 4; j++) {
            s0[j] += __shfl_xor(s0[j], 1); s0[j] += __shfl_xor(s0[j], 2);
            s0[j] += __shfl_xor(s0[j], 4); s0[j] += __shfl_xor(s0[j], 8);
            s1[j] += __shfl_xor(s1[j], 1); s1[j] += __shfl_xor(s1[j], 2);
            s1[j] += __shfl_xor(s1[j], 4); s1[j] += __shfl_xor(s1[j], 8);
            s2[j] += __shfl_xor(s2[j], 1); s2[j] += __shfl_xor(s2[j], 2);
            s2[j] += __shfl_xor(s2[j], 4); s2[j] += __shfl_xor(s2[j], 8);
        }
        int nbase = n0 + wv * 64 + g * 16 + hi * 4;
        if (lo == 0) {
            float4 o4 = make_float4(s0[0] + b2l[0], s0[1] + b2l[0], s0[2] + b2l[0], s0[3] + b2l[0]);
            *(float4*)(out + ((size_t)b * 3 + 0) * N_ + nbase) = o4;
        } else if (lo == 1) {
            float4 o4 = make_float4(s1[0] + b2l[1], s1[1] + b2l[1], s1[2] + b2l[1], s1[3] + b2l[1]);
            *(float4*)(out + ((size_t)b * 3 + 1) * N_ + nbase) = o4;
        } else if (lo == 2) {
            float4 o4 = make_float4(s2[0] + b2l[2], s2[1] + b2l[2], s2[2] + b2l[2], s2[3] + b2l[2]);
            *(float4*)(out + ((size_t)b * 3 + 2) * N_ + nbase) = o4;
        }
    }
}

extern "C" void kernel_launch(void* const* d_in, const int* in_sizes, int n_in,
                              void* d_out, int out_size, void* d_ws, size_t ws_size,
                              hipStream_t stream) {
    const float* coords  = (const float*)d_in[0];
    const float* feats   = (const float*)d_in[1];
    const float* conv_w  = (const float*)d_in[2];
    const float* conv_b  = (const float*)d_in[3];
    const float* wq      = (const float*)d_in[4];
    const float* wk      = (const float*)d_in[5];
    const float* wv      = (const float*)d_in[6];
    const float* wo      = (const float*)d_in[7];
    const float* se_w1   = (const float*)d_in[8];
    const float* se_b1   = (const float*)d_in[9];
    const float* se_w2   = (const float*)d_in[10];
    const float* se_b2   = (const float*)d_in[11];
    const float* point_w = (const float*)d_in[12];
    const float* point_b = (const float*)d_in[13];
    const float* cls_w1  = (const float*)d_in[14];
    const float* cls_b1  = (const float*)d_in[15];
    const float* cls_w2  = (const float*)d_in[16];
    const float* cls_b2  = (const float*)d_in[17];

    float* ws = (float*)d_ws;
    float* vsum   = ws;                        // 98304
    float* cnt    = ws + 98304;                // 16384
    float* semean = ws + 114688;               // 256
    float* vox    = ws + 115200;               // region reused as xattT (bf16)
    float* voxT   = vox + 1048576;             // f32 [b][s][64]: conv2 -> qkv4 + wo residual
    unsigned short* qT = (unsigned short*)(voxT + 1048576);
    unsigned short* kT = qT + 1048576;
    unsigned short* vT = kT + 1048576;
    float* Opart  = (float*)(vT + 1048576);    // 2097152 f32: vox partials, then attn partials
    float* lpart  = Opart + 2097152;           // 32768
    unsigned short* xattT = (unsigned short*)vox;   // bf16 [b][s][64]

    hipMemsetAsync(semean, 0, 256 * sizeof(float), stream);   // semean only (atomic accum)
    k_vox_part<<<64, 1024, 0, stream>>>(coords, feats, Opart);
    k_vox_reduce<<<448, 256, 0, stream>>>(Opart, vsum, cnt);
    k_conv2<<<512, 256, 0, stream>>>(vsum, cnt, conv_w, conv_b, voxT);
    k_qkv4<<<256, 256, 0, stream>>>(voxT, wq, wk, wv, qT, kT, vT);
    k_attn11<<<512, 256, 0, stream>>>(qT, kT, vT, Opart, lpart);
    k_wo_mfma<<<256, 256, 0, stream>>>(Opart, lpart, wo, voxT, xattT, semean);
    k_point<<<512, 256, 0, stream>>>(coords, feats, xattT, semean,
                                     se_w1, se_b1, se_w2, se_b2, point_w, point_b,
                                     cls_w1, cls_b1, cls_w2, cls_b2, (float*)d_out);
}

// Round 21
// 155.039 us; speedup vs baseline: 1.1107x; 1.0096x over previous
//
#include <hip/hip_runtime.h>
#include <hip/hip_bf16.h>
#include <math.h>

#define B_ 4
#define N_ 32768
#define CIN 6
#define C_ 64
#define R_ 16
#define S_ 4096

typedef __attribute__((ext_vector_type(8))) __bf16 bf16x8;
typedef __attribute__((ext_vector_type(8))) short short8;
typedef __attribute__((ext_vector_type(4))) short s16x4;
typedef __attribute__((ext_vector_type(4))) float f32x4;

#define MFMA16(a, b, c) __builtin_amdgcn_mfma_f32_16x16x32_bf16((a), (b), (c), 0, 0, 0)

__device__ inline f32x4 zero4() {
    f32x4 z;
    z[0] = 0.f; z[1] = 0.f; z[2] = 0.f; z[3] = 0.f;
    return z;
}

__device__ inline unsigned short f2bf(float f) {
    unsigned u = __builtin_bit_cast(unsigned, f);
    u += 0x7fffu + ((u >> 16) & 1u);          // RNE
    return (unsigned short)(u >> 16);
}

__device__ inline float bf2f(unsigned short s) {
    unsigned u = ((unsigned)s) << 16;
    return __builtin_bit_cast(float, u);
}

__device__ inline short8 pack8(float4 a, float4 b) {
    short8 r;
    r[0] = (short)f2bf(a.x); r[1] = (short)f2bf(a.y); r[2] = (short)f2bf(a.z); r[3] = (short)f2bf(a.w);
    r[4] = (short)f2bf(b.x); r[5] = (short)f2bf(b.y); r[6] = (short)f2bf(b.z); r[7] = (short)f2bf(b.w);
    return r;
}

__device__ inline bf16x8 pack8b(float4 a, float4 b) {
    return __builtin_bit_cast(bf16x8, pack8(a, b));
}

// ---------------- K1a: per-block partial LDS histograms (no global atomics) ----------------
__global__ __launch_bounds__(1024) void k_vox_part(const float* __restrict__ coords,
                                                   const float* __restrict__ feats,
                                                   float* __restrict__ part) {
    __shared__ float hist[7 * S_];             // 114688 B
    int bid = blockIdx.x;                      // 64: b(4) x p(16)
    int b = bid >> 4, p = bid & 15;
    int tid = threadIdx.x;
    for (int i = tid; i < 7 * S_; i += 1024) hist[i] = 0.f;
    __syncthreads();
    const float* cb = coords + (size_t)b * 3 * N_;
    const float* fb = feats + (size_t)b * CIN * N_;
#pragma unroll
    for (int it = 0; it < 2; ++it) {
        int n = p * 2048 + it * 1024 + tid;
        float x = cb[n], y = cb[N_ + n], z = cb[2 * N_ + n];
        int vx = min(max((int)floorf(x * R_), 0), R_ - 1);
        int vy = min(max((int)floorf(y * R_), 0), R_ - 1);
        int vz = min(max((int)floorf(z * R_), 0), R_ - 1);
        int cell = (vx * R_ + vy) * R_ + vz;
#pragma unroll
        for (int f = 0; f < CIN; f++) atomicAdd(&hist[f * S_ + cell], fb[f * N_ + n]);
        atomicAdd(&hist[6 * S_ + cell], 1.0f);
    }
    __syncthreads();
    float* dst = part + (size_t)bid * (7 * S_);
    for (int i = tid; i < 7 * S_; i += 1024) dst[i] = hist[i];
}

// ---------------- K1b: fold 16 partials -> vsum, cnt ----------------
__global__ __launch_bounds__(256) void k_vox_reduce(const float* __restrict__ part,
                                                    float* __restrict__ vsum, float* __restrict__ cnt) {
    int idx = blockIdx.x * 256 + threadIdx.x;  // 4 * 28672 = 114688 threads
    int b = idx / (7 * S_);
    int r = idx - b * (7 * S_);
    const float* pb = part + (size_t)b * 16 * (7 * S_) + r;
    float s = 0.f;
#pragma unroll
    for (int p = 0; p < 16; p++) s += pb[(size_t)p * (7 * S_)];
    if (r < CIN * S_) vsum[(size_t)b * CIN * S_ + r] = s;
    else cnt[b * S_ + (r - CIN * S_)] = s;
}

// ---------------- K2: conv + fused mean-division -> voxT f32 [b][s][64] ----------------
__global__ __launch_bounds__(256) void k_conv2(const float* __restrict__ vsum, const float* __restrict__ cnt,
                                               const float* __restrict__ w, const float* __restrict__ bias,
                                               float* __restrict__ voxT) {
    __shared__ float msl[3][CIN][256];
    __shared__ float wl[8 * 162];
    int bid = blockIdx.x;                 // b(4) x x(16) x og(8) = 512
    int b = bid >> 7;
    int x = (bid >> 3) & 15;
    int o0 = (bid & 7) * 8;
    int tid = threadIdx.x;
    for (int i = tid; i < 8 * 162; i += 256) wl[i] = w[o0 * 162 + i];
#pragma unroll
    for (int sl = 0; sl < 3; sl++) {
        int xx = x - 1 + sl;
        if (xx >= 0 && xx < 16) {
            float c = cnt[b * S_ + xx * 256 + tid];
            float invc = 1.f / fmaxf(c, 1.f);
#pragma unroll
            for (int i = 0; i < CIN; i++)
                msl[sl][i][tid] = vsum[((size_t)b * CIN + i) * S_ + xx * 256 + tid] * invc;
        } else {
#pragma unroll
            for (int i = 0; i < CIN; i++) msl[sl][i][tid] = 0.f;
        }
    }
    __syncthreads();
    int y = tid >> 4, z = tid & 15;
    float acc[8];
#pragma unroll
    for (int oj = 0; oj < 8; oj++) acc[oj] = bias[o0 + oj];
#pragma unroll
    for (int dx = 0; dx < 3; dx++) {
#pragma unroll
        for (int dy = 0; dy < 3; dy++) {
            int yy = y + dy - 1;
            if ((unsigned)yy >= 16u) continue;
#pragma unroll
            for (int dz = 0; dz < 3; dz++) {
                int zz = z + dz - 1;
                if ((unsigned)zz >= 16u) continue;
                int idx = yy * 16 + zz;
#pragma unroll
                for (int i = 0; i < CIN; i++) {
                    float m = msl[dx][i][idx];
                    int wb = i * 27 + dx * 9 + dy * 3 + dz;
#pragma unroll
                    for (int oj = 0; oj < 8; oj++) acc[oj] += wl[oj * 162 + wb] * m;
                }
            }
        }
    }
    int cell = x * 256 + tid;
    float* dst = voxT + ((size_t)b * S_ + cell) * 64 + o0;
    *(float4*)dst = make_float4(fmaxf(acc[0], 0.f), fmaxf(acc[1], 0.f), fmaxf(acc[2], 0.f), fmaxf(acc[3], 0.f));
    *(float4*)(dst + 4) = make_float4(fmaxf(acc[4], 0.f), fmaxf(acc[5], 0.f), fmaxf(acc[6], 0.f), fmaxf(acc[7], 0.f));
}

// ---------------- K3: qkv via MFMA -> qT,kT [s][64]; vT [c][t] ----------------
__global__ __launch_bounds__(256) void k_qkv4(const float* __restrict__ voxT,
                                              const float* __restrict__ wq, const float* __restrict__ wk,
                                              const float* __restrict__ wv,
                                              unsigned short* __restrict__ qT, unsigned short* __restrict__ kT,
                                              unsigned short* __restrict__ vT) {
    int bid = blockIdx.x;                 // 256: b(4) x chunk(64)
    int b = bid >> 6;
    int srow = (bid & 63) * 64 + (threadIdx.x >> 6) * 16;   // 16 rows per wave
    int lane = threadIdx.x & 63;
    int lo = lane & 15, hi = lane >> 4;

    const float* xr = voxT + ((size_t)b * S_ + srow + lo) * 64 + hi * 8;
    bf16x8 a0 = pack8b(*(const float4*)xr, *(const float4*)(xr + 4));
    bf16x8 a1 = pack8b(*(const float4*)(xr + 32), *(const float4*)(xr + 36));

#pragma unroll
    for (int m = 0; m < 3; m++) {
        const float* wp = (m == 0) ? wq : (m == 1) ? wk : wv;
#pragma unroll
        for (int oc = 0; oc < 4; oc++) {
            const float* wr = wp + (oc * 16 + lo) * 64 + hi * 8;
            bf16x8 b0 = pack8b(*(const float4*)wr, *(const float4*)(wr + 4));
            bf16x8 b1 = pack8b(*(const float4*)(wr + 32), *(const float4*)(wr + 36));
            f32x4 acc = zero4();
            acc = MFMA16(a0, b0, acc);
            acc = MFMA16(a1, b1, acc);
            if (m < 2) {
                unsigned short* dst = ((m == 0) ? qT : kT) + ((size_t)b * S_ + srow + hi * 4) * 64 + oc * 16 + lo;
#pragma unroll
                for (int j = 0; j < 4; j++) dst[(size_t)j * 64] = f2bf(acc[j]);
            } else {
                s16x4 pk;
#pragma unroll
                for (int j = 0; j < 4; j++) pk[j] = (short)f2bf(acc[j]);
                *(s16x4*)(vT + ((size_t)b * 64 + oc * 16 + lo) * S_ + srow + hi * 4) = pk;
            }
        }
    }
}

// ---------------- K4: attn — shared LDS K/V tiles, T14 staging, waves own disjoint 16-row q-tiles ----------------
__global__ __launch_bounds__(256) void k_attn11(const unsigned short* __restrict__ qT,
                                                const unsigned short* __restrict__ kT,
                                                const unsigned short* __restrict__ vT,
                                                float* __restrict__ Opart, float* __restrict__ lpart) {
    __shared__ __align__(16) char Kl[8192];     // 64 t-rows x 128B, XOR-swizzled slots
    __shared__ __align__(16) char Vl[8192];     // 64 c-rows x 128B, XOR-swizzled slots
    __shared__ __align__(16) char PsB[8192];    // per-wave 2KB P buffer
    int bid = blockIdx.x;                       // 512: b(4) x qt(64) x half(2)
    int b = bid >> 7;
    int qt = (bid >> 1) & 63;
    int half = bid & 1;
    int sq0 = qt * 64;
    int tid = threadIdx.x;
    int w = tid >> 6, lane = tid & 63;
    int lo = lane & 15, hi = lane >> 4;
    char* Ps = PsB + w * 2048;

    const unsigned short* qb = qT + ((size_t)b * S_ + sq0 + w * 16) * 64;
    bf16x8 qf0 = __builtin_bit_cast(bf16x8, *(const short8*)(qb + lo * 64 + hi * 8));
    bf16x8 qf1 = __builtin_bit_cast(bf16x8, *(const short8*)(qb + lo * 64 + hi * 8 + 32));

    f32x4 O[4];
    float l[4];
#pragma unroll
    for (int cc = 0; cc < 4; cc++) O[cc] = zero4();
#pragma unroll
    for (int j = 0; j < 4; j++) l[j] = 0.f;

    const char* kTb = (const char*)(kT + (size_t)b * S_ * 64);   // t-row = 128B
    const char* vTb = (const char*)(vT + (size_t)b * 64 * S_);   // c-row = 8192B
    int tbase = half * 2048;

    int swz = ((tid >> 3) & 7) << 4;
    int x0 = tid * 16;
    int vrow = tid >> 3, vslot16 = (tid & 7) * 16;

    short8 g0, g1, g2, g3;
    {
        const char* ktile = kTb + (size_t)tbase * 128;
        g0 = *(const short8*)(ktile + x0);
        g1 = *(const short8*)(ktile + x0 + 4096);
        const char* vt0 = vTb + (size_t)tbase * 2;
        g2 = *(const short8*)(vt0 + (size_t)vrow * 8192 + vslot16);
        g3 = *(const short8*)(vt0 + (size_t)(vrow + 32) * 8192 + vslot16);
    }

    for (int it = 0; it < 32; ++it) {
        __syncthreads();
        *(short8*)(Kl + (x0 ^ swz)) = g0;
        *(short8*)(Kl + ((x0 + 4096) ^ swz)) = g1;
        *(short8*)(Vl + (x0 ^ swz)) = g2;
        *(short8*)(Vl + ((x0 + 4096) ^ swz)) = g3;
        __syncthreads();
        if (it + 1 < 32) {
            int t0n = tbase + (it + 1) * 64;
            const char* ktile = kTb + (size_t)t0n * 128;
            g0 = *(const short8*)(ktile + x0);
            g1 = *(const short8*)(ktile + x0 + 4096);
            const char* vtn = vTb + (size_t)t0n * 2;
            g2 = *(const short8*)(vtn + (size_t)vrow * 8192 + vslot16);
            g3 = *(const short8*)(vtn + (size_t)(vrow + 32) * 8192 + vslot16);
        }
#pragma unroll
        for (int ct = 0; ct < 4; ct++) {
            int t = ct * 16 + lo;
            int tswz = (t & 7) << 4;
            bf16x8 kf0 = __builtin_bit_cast(bf16x8, *(const short8*)(Kl + (t * 128 + ((hi * 16) ^ tswz))));
            bf16x8 kf1 = __builtin_bit_cast(bf16x8, *(const short8*)(Kl + (t * 128 + ((64 + hi * 16) ^ tswz))));
            f32x4 z = zero4();
            z = MFMA16(qf0, kf0, z);
            f32x4 Sacc = MFMA16(qf1, kf1, z);
#pragma unroll
            for (int j = 0; j < 4; j++) {
                float p = __expf(Sacc[j] * 0.125f);
                l[j] += p;
                int r = hi * 4 + j;
                int pswz = (r & 7) << 4;
                *(unsigned short*)(Ps + ((r * 128 + t * 2) ^ pswz)) = f2bf(p);
            }
        }
        int rswz = (lo & 7) << 4;
        bf16x8 pa0 = __builtin_bit_cast(bf16x8, *(const short8*)(Ps + ((lo * 128 + hi * 16) ^ rswz)));
        bf16x8 pa1 = __builtin_bit_cast(bf16x8, *(const short8*)(Ps + ((lo * 128 + 64 + hi * 16) ^ rswz)));
#pragma unroll
        for (int cc = 0; cc < 4; cc++) {
            int c = cc * 16 + lo;
            int cswz = (c & 7) << 4;
            bf16x8 vf0 = __builtin_bit_cast(bf16x8, *(const short8*)(Vl + (c * 128 + ((hi * 16) ^ cswz))));
            bf16x8 vf1 = __builtin_bit_cast(bf16x8, *(const short8*)(Vl + (c * 128 + ((64 + hi * 16) ^ cswz))));
            O[cc] = MFMA16(pa0, vf0, O[cc]);
            O[cc] = MFMA16(pa1, vf1, O[cc]);
        }
    }

    float* ob = Opart + ((size_t)(half * B_ + b) * S_ + sq0 + w * 16) * 64;
#pragma unroll
    for (int cc = 0; cc < 4; cc++)
#pragma unroll
        for (int j = 0; j < 4; j++)
            ob[(size_t)(hi * 4 + j) * 64 + cc * 16 + lo] = O[cc][j];
#pragma unroll
    for (int j = 0; j < 4; j++) {
        float s = l[j];
        s += __shfl_xor(s, 1);
        s += __shfl_xor(s, 2);
        s += __shfl_xor(s, 4);
        s += __shfl_xor(s, 8);
        if (lo == 0)
            lpart[(size_t)(half * B_ + b) * S_ + sq0 + w * 16 + hi * 4 + j] = s;
    }
}

// ---------------- K5: combine(2 halves) + Wo MFMA + residual + SE-mean -> xattT bf16 ----------------
__global__ __launch_bounds__(256) void k_wo_mfma(const float* __restrict__ Opart,
                                                 const float* __restrict__ lpart,
                                                 const float* __restrict__ wo,
                                                 const float* __restrict__ voxT,
                                                 unsigned short* __restrict__ xattT,
                                                 float* __restrict__ semean) {
    __shared__ float sem[64];
    int tid = threadIdx.x;
    if (tid < 64) sem[tid] = 0.f;
    __syncthreads();
    int wid = tid >> 6, lane = tid & 63;
    int lo = lane & 15, hi = lane >> 4;
    int r0 = blockIdx.x * 64 + wid * 16;               // global row (b*S + s)
    int bidx = r0 >> 12;
    int row = r0 + lo;
    const int BS = B_ * S_;

    float L = lpart[row] + lpart[BS + row];
    float inv = 1.f / L;
    float4 q0 = make_float4(0.f, 0.f, 0.f, 0.f), q1 = q0, q2 = q0, q3 = q0;
#pragma unroll
    for (int sp = 0; sp < 2; sp++) {
        const float* orow = Opart + ((size_t)sp * BS + row) * 64 + hi * 8;
        float4 t0 = *(const float4*)(orow);
        float4 t1 = *(const float4*)(orow + 4);
        float4 t2 = *(const float4*)(orow + 32);
        float4 t3 = *(const float4*)(orow + 36);
        q0.x += t0.x; q0.y += t0.y; q0.z += t0.z; q0.w += t0.w;
        q1.x += t1.x; q1.y += t1.y; q1.z += t1.z; q1.w += t1.w;
        q2.x += t2.x; q2.y += t2.y; q2.z += t2.z; q2.w += t2.w;
        q3.x += t3.x; q3.y += t3.y; q3.z += t3.z; q3.w += t3.w;
    }
    q0.x *= inv; q0.y *= inv; q0.z *= inv; q0.w *= inv;
    q1.x *= inv; q1.y *= inv; q1.z *= inv; q1.w *= inv;
    q2.x *= inv; q2.y *= inv; q2.z *= inv; q2.w *= inv;
    q3.x *= inv; q3.y *= inv; q3.z *= inv; q3.w *= inv;
    bf16x8 a0 = pack8b(q0, q1);
    bf16x8 a1 = pack8b(q2, q3);

    float colsum[4];
#pragma unroll
    for (int cc = 0; cc < 4; cc++) {
        int o = cc * 16 + lo;
        float4 f0 = *(const float4*)(wo + o * 64 + hi * 8);
        float4 f1 = *(const float4*)(wo + o * 64 + hi * 8 + 4);
        bf16x8 b0 = pack8b(f0, f1);
        float4 f2 = *(const float4*)(wo + o * 64 + 32 + hi * 8);
        float4 f3 = *(const float4*)(wo + o * 64 + 32 + hi * 8 + 4);
        bf16x8 b1 = pack8b(f2, f3);
        f32x4 acc = zero4();
        acc = MFMA16(a0, b0, acc);
        acc = MFMA16(a1, b1, acc);
        float cs = 0.f;
#pragma unroll
        for (int j = 0; j < 4; j++) {
            size_t idx = (size_t)(r0 + hi * 4 + j) * 64 + o;
            float xn = acc[j] + voxT[idx];
            xattT[idx] = f2bf(xn);
            cs += xn;
        }
        cs += __shfl_xor(cs, 16);
        cs += __shfl_xor(cs, 32);
        colsum[cc] = cs;
    }
    if (hi == 0) {
#pragma unroll
        for (int cc = 0; cc < 4; cc++) atomicAdd(&sem[cc * 16 + lo], colsum[cc]);
    }
    __syncthreads();
    if (tid < 64) atomicAdd(&semean[bidx * 64 + tid], sem[tid]);
}

// ---------------- K8: SE gate + devoxelize (two-pass 32-ch) + point MLP + MFMA classifier ----------------
__global__ __launch_bounds__(256) void k_point(const float* __restrict__ coords, const float* __restrict__ feats,
                                               const unsigned short* __restrict__ xt, const float* __restrict__ semean,
                                               const float* __restrict__ sw1, const float* __restrict__ sb1,
                                               const float* __restrict__ sw2, const float* __restrict__ sb2,
                                               const float* __restrict__ pw,
                                               const float* __restrict__ pb, const float* __restrict__ w1,
                                               const float* __restrict__ b1, const float* __restrict__ w2,
                                               const float* __restrict__ b2, float* __restrict__ out) {
    __shared__ unsigned short fl[256 * 64];    // 32KB fused bf16, XOR-swizzled rows
    __shared__ float pwl[64 * 6];
    __shared__ float pbl[64];
    __shared__ float b1l[128];
    __shared__ float w2l[3 * 128];
    __shared__ float b2l[3];
    __shared__ float gl[64];
    __shared__ float sml[64];
    __shared__ float hh[8];
    int tid = threadIdx.x;
    int gidx0 = blockIdx.x * 256;
    int b = gidx0 >> 15, n0 = gidx0 & (N_ - 1);
    int n = n0 + tid;
    for (int i = tid; i < 384; i += 256) { pwl[i] = pw[i]; w2l[i] = w2[i]; }
    if (tid < 128) b1l[tid] = b1[tid];
    if (tid < 64) { pbl[tid] = pb[tid]; sml[tid] = semean[b * 64 + tid] * (1.0f / S_); }
    if (tid < 3) b2l[tid] = b2[tid];
    __syncthreads();
    if (tid < 8) {
        float a = sb1[tid];
#pragma unroll
        for (int i = 0; i < 64; i++) a += sw1[tid * 64 + i] * sml[i];
        hh[tid] = fmaxf(a, 0.f);
    }
    __syncthreads();
    if (tid < 64) {
        float g = sb2[tid];
#pragma unroll
        for (int j = 0; j < 8; j++) g += sw2[tid * 8 + j] * hh[j];
        gl[tid] = 1.f / (1.f + __expf(-g));
    }
    __syncthreads();

    const float* cb = coords + (size_t)b * 3 * N_;
    float px = fminf(fmaxf(cb[n] * R_ - 0.5f, 0.f), 15.f);
    float py = fminf(fmaxf(cb[N_ + n] * R_ - 0.5f, 0.f), 15.f);
    float pz = fminf(fmaxf(cb[2 * N_ + n] * R_ - 0.5f, 0.f), 15.f);
    int x0 = (int)floorf(px); float wx = px - x0; int x1 = min(x0 + 1, 15);
    int y0 = (int)floorf(py); float wy = py - y0; int y1 = min(y0 + 1, 15);
    int z0 = (int)floorf(pz); float wz = pz - z0; int z1 = min(z0 + 1, 15);
    float fv[6];
#pragma unroll
    for (int i = 0; i < 6; i++) fv[i] = feats[((size_t)b * 6 + i) * N_ + n];

    // precompute corner offsets + weights (static-indexed -> registers)
    int coff[8];
    float cwgt[8];
#pragma unroll
    for (int dx = 0; dx < 2; dx++)
#pragma unroll
        for (int dy = 0; dy < 2; dy++)
#pragma unroll
            for (int dz = 0; dz < 2; dz++) {
                int k = dx * 4 + dy * 2 + dz;
                int xi = dx ? x1 : x0, yi = dy ? y1 : y0, zi = dz ? z1 : z0;
                coff[k] = ((xi * 16 + yi) * 16 + zi) * 64;
                cwgt[k] = (dx ? wx : 1.f - wx) * (dy ? wy : 1.f - wy) * (dz ? wz : 1.f - wz);
            }

    const unsigned short* xb = xt + (size_t)b * S_ * 64;
    // two sequential 32-channel passes to halve the register peak
#pragma unroll 1
    for (int h = 0; h < 2; h++) {
        float fused[32];
#pragma unroll
        for (int c = 0; c < 32; c++) fused[c] = 0.f;
#pragma unroll
        for (int k = 0; k < 8; k++) {
            const short8* g = (const short8*)(xb + coff[k] + h * 32);
            float wgt = cwgt[k];
#pragma unroll
            for (int c8 = 0; c8 < 4; c8++) {
                short8 gv = g[c8];
#pragma unroll
                for (int i = 0; i < 8; i++)
                    fused[c8 * 8 + i] += wgt * bf2f((unsigned short)gv[i]);
            }
        }
#pragma unroll
        for (int c = 0; c < 32; c++) {
            int cc = h * 32 + c;
            float pt = pbl[cc];
#pragma unroll
            for (int i = 0; i < 6; i++) pt += pwl[cc * 6 + i] * fv[i];
            pt = fmaxf(pt, 0.f);
            fused[c] = fmaxf(fused[c] * gl[cc] + pt, 0.f);
        }
#pragma unroll
        for (int ch = 0; ch < 4; ch++) {
            short8 v;
#pragma unroll
            for (int i = 0; i < 8; i++) v[i] = (short)f2bf(fused[ch * 8 + i]);
            int byte = tid * 128 + h * 64 + ch * 16;
            *(short8*)((char*)fl + (byte ^ ((tid & 7) << 4))) = v;
        }
    }
    __syncthreads();

    int wv = tid >> 6, lane = tid & 63;
    int lo = lane & 15, hi = lane >> 4;
    bf16x8 bw[16];
#pragma unroll
    for (int th = 0; th < 8; th++) {
#pragma unroll
        for (int kf = 0; kf < 2; kf++) {
            const float* wr = w1 + (th * 16 + lo) * 64 + kf * 32 + hi * 8;
            bw[th * 2 + kf] = pack8b(*(const float4*)wr, *(const float4*)(wr + 4));
        }
    }
#pragma unroll
    for (int g = 0; g < 4; g++) {
        int row = wv * 64 + g * 16 + lo;
        int swz = (row & 7) << 4;
        bf16x8 a0 = __builtin_bit_cast(bf16x8, *(const short8*)((char*)fl + ((row * 128 + hi * 16) ^ swz)));
        bf16x8 a1 = __builtin_bit_cast(bf16x8, *(const short8*)((char*)fl + ((row * 128 + 64 + hi * 16) ^ swz)));
        f32x4 acc[8];
#pragma unroll
        for (int th = 0; th < 8; th++) {
            acc[th] = zero4();
            acc[th] = MFMA16(a0, bw[th * 2], acc[th]);
            acc[th] = MFMA16(a1, bw[th * 2 + 1], acc[th]);
        }
        float s0[4] = {0.f, 0.f, 0.f, 0.f};
        float s1[4] = {0.f, 0.f, 0.f, 0.f};
        float s2[4] = {0.f, 0.f, 0.f, 0.f};
#pragma unroll
        for (int th = 0; th < 8; th++) {
            int hidx = th * 16 + lo;
            float w2o0 = w2l[hidx];
            float w2o1 = w2l[128 + hidx];
            float w2o2 = w2l[256 + hidx];
            float bias = b1l[hidx];
#pragma unroll
            for (int j = 0; j < 4; j++) {
                float hj = fmaxf(acc[th][j] + bias, 0.f);
                s0[j] += hj * w2o0;
                s1[j] += hj * w2o1;
                s2[j] += hj * w2o2;
            }
        }
#pragma unroll
        for (int j = 0; j < 4; j++) {
            s0[j] += __shfl_xor(s0[j], 1); s0[j] += __shfl_xor(s0[j], 2);
            s0[j] += __shfl_xor(s0[j], 4); s0[j] += __shfl_xor(s0[j], 8);
            s1[j] += __shfl_xor(s1[j], 1); s1[j] += __shfl_xor(s1[j], 2);
            s1[j] += __shfl_xor(s1[j], 4); s1[j] += __shfl_xor(s1[j], 8);
            s2[j] += __shfl_xor(s2[j], 1); s2[j] += __shfl_xor(s2[j], 2);
            s2[j] += __shfl_xor(s2[j], 4); s2[j] += __shfl_xor(s2[j], 8);
        }
        int nbase = n0 + wv * 64 + g * 16 + hi * 4;
        if (lo == 0) {
            float4 o4 = make_float4(s0[0] + b2l[0], s0[1] + b2l[0], s0[2] + b2l[0], s0[3] + b2l[0]);
            *(float4*)(out + ((size_t)b * 3 + 0) * N_ + nbase) = o4;
        } else if (lo == 1) {
            float4 o4 = make_float4(s1[0] + b2l[1], s1[1] + b2l[1], s1[2] + b2l[1], s1[3] + b2l[1]);
            *(float4*)(out + ((size_t)b * 3 + 1) * N_ + nbase) = o4;
        } else if (lo == 2) {
            float4 o4 = make_float4(s2[0] + b2l[2], s2[1] + b2l[2], s2[2] + b2l[2], s2[3] + b2l[2]);
            *(float4*)(out + ((size_t)b * 3 + 2) * N_ + nbase) = o4;
        }
    }
}

extern "C" void kernel_launch(void* const* d_in, const int* in_sizes, int n_in,
                              void* d_out, int out_size, void* d_ws, size_t ws_size,
                              hipStream_t stream) {
    const float* coords  = (const float*)d_in[0];
    const float* feats   = (const float*)d_in[1];
    const float* conv_w  = (const float*)d_in[2];
    const float* conv_b  = (const float*)d_in[3];
    const float* wq      = (const float*)d_in[4];
    const float* wk      = (const float*)d_in[5];
    const float* wv      = (const float*)d_in[6];
    const float* wo      = (const float*)d_in[7];
    const float* se_w1   = (const float*)d_in[8];
    const float* se_b1   = (const float*)d_in[9];
    const float* se_w2   = (const float*)d_in[10];
    const float* se_b2   = (const float*)d_in[11];
    const float* point_w = (const float*)d_in[12];
    const float* point_b = (const float*)d_in[13];
    const float* cls_w1  = (const float*)d_in[14];
    const float* cls_b1  = (const float*)d_in[15];
    const float* cls_w2  = (const float*)d_in[16];
    const float* cls_b2  = (const float*)d_in[17];

    float* ws = (float*)d_ws;
    float* vsum   = ws;                        // 98304
    float* cnt    = ws + 98304;                // 16384
    float* semean = ws + 114688;               // 256
    float* vox    = ws + 115200;               // region reused as xattT (bf16)
    float* voxT   = vox + 1048576;             // f32 [b][s][64]: conv2 -> qkv4 + wo residual
    unsigned short* qT = (unsigned short*)(voxT + 1048576);
    unsigned short* kT = qT + 1048576;
    unsigned short* vT = kT + 1048576;
    float* Opart  = (float*)(vT + 1048576);    // 2097152 f32: vox partials, then attn partials
    float* lpart  = Opart + 2097152;           // 32768
    unsigned short* xattT = (unsigned short*)vox;   // bf16 [b][s][64]

    hipMemsetAsync(semean, 0, 256 * sizeof(float), stream);   // semean only (atomic accum)
    k_vox_part<<<64, 1024, 0, stream>>>(coords, feats, Opart);
    k_vox_reduce<<<448, 256, 0, stream>>>(Opart, vsum, cnt);
    k_conv2<<<512, 256, 0, stream>>>(vsum, cnt, conv_w, conv_b, voxT);
    k_qkv4<<<256, 256, 0, stream>>>(voxT, wq, wk, wv, qT, kT, vT);
    k_attn11<<<512, 256, 0, stream>>>(qT, kT, vT, Opart, lpart);
    k_wo_mfma<<<256, 256, 0, stream>>>(Opart, lpart, wo, voxT, xattT, semean);
    k_point<<<512, 256, 0, stream>>>(coords, feats, xattT, semean,
                                     se_w1, se_b1, se_w2, se_b2, point_w, point_b,
                                     cls_w1, cls_b1, cls_w2, cls_b2, (float*)d_out);
}

// Round 22
// 151.685 us; speedup vs baseline: 1.1352x; 1.0221x over previous
//
#include <hip/hip_runtime.h>
#include <hip/hip_bf16.h>
#include <math.h>

#define B_ 4
#define N_ 32768
#define CIN 6
#define C_ 64
#define R_ 16
#define S_ 4096

typedef __attribute__((ext_vector_type(8))) __bf16 bf16x8;
typedef __attribute__((ext_vector_type(8))) short short8;
typedef __attribute__((ext_vector_type(4))) short s16x4;
typedef __attribute__((ext_vector_type(4))) float f32x4;

#define MFMA16(a, b, c) __builtin_amdgcn_mfma_f32_16x16x32_bf16((a), (b), (c), 0, 0, 0)

__device__ inline f32x4 zero4() {
    f32x4 z;
    z[0] = 0.f; z[1] = 0.f; z[2] = 0.f; z[3] = 0.f;
    return z;
}

__device__ inline unsigned short f2bf(float f) {
    unsigned u = __builtin_bit_cast(unsigned, f);
    u += 0x7fffu + ((u >> 16) & 1u);          // RNE
    return (unsigned short)(u >> 16);
}

__device__ inline float bf2f(unsigned short s) {
    unsigned u = ((unsigned)s) << 16;
    return __builtin_bit_cast(float, u);
}

__device__ inline short8 pack8(float4 a, float4 b) {
    short8 r;
    r[0] = (short)f2bf(a.x); r[1] = (short)f2bf(a.y); r[2] = (short)f2bf(a.z); r[3] = (short)f2bf(a.w);
    r[4] = (short)f2bf(b.x); r[5] = (short)f2bf(b.y); r[6] = (short)f2bf(b.z); r[7] = (short)f2bf(b.w);
    return r;
}

__device__ inline bf16x8 pack8b(float4 a, float4 b) {
    return __builtin_bit_cast(bf16x8, pack8(a, b));
}

// ---------------- K1a: per-block partial LDS histograms (no global atomics) ----------------
__global__ __launch_bounds__(1024) void k_vox_part(const float* __restrict__ coords,
                                                   const float* __restrict__ feats,
                                                   float* __restrict__ part) {
    __shared__ float hist[7 * S_];             // 114688 B
    int bid = blockIdx.x;                      // 64: b(4) x p(16)
    int b = bid >> 4, p = bid & 15;
    int tid = threadIdx.x;
    for (int i = tid; i < 7 * S_; i += 1024) hist[i] = 0.f;
    __syncthreads();
    const float* cb = coords + (size_t)b * 3 * N_;
    const float* fb = feats + (size_t)b * CIN * N_;
#pragma unroll
    for (int it = 0; it < 2; ++it) {
        int n = p * 2048 + it * 1024 + tid;
        float x = cb[n], y = cb[N_ + n], z = cb[2 * N_ + n];
        int vx = min(max((int)floorf(x * R_), 0), R_ - 1);
        int vy = min(max((int)floorf(y * R_), 0), R_ - 1);
        int vz = min(max((int)floorf(z * R_), 0), R_ - 1);
        int cell = (vx * R_ + vy) * R_ + vz;
#pragma unroll
        for (int f = 0; f < CIN; f++) atomicAdd(&hist[f * S_ + cell], fb[f * N_ + n]);
        atomicAdd(&hist[6 * S_ + cell], 1.0f);
    }
    __syncthreads();
    float* dst = part + (size_t)bid * (7 * S_);
    for (int i = tid; i < 7 * S_; i += 1024) dst[i] = hist[i];
}

// ---------------- K1b: fold 16 partials -> vsum, cnt ----------------
__global__ __launch_bounds__(256) void k_vox_reduce(const float* __restrict__ part,
                                                    float* __restrict__ vsum, float* __restrict__ cnt) {
    int idx = blockIdx.x * 256 + threadIdx.x;  // 4 * 28672 = 114688 threads
    int b = idx / (7 * S_);
    int r = idx - b * (7 * S_);
    const float* pb = part + (size_t)b * 16 * (7 * S_) + r;
    float s = 0.f;
#pragma unroll
    for (int p = 0; p < 16; p++) s += pb[(size_t)p * (7 * S_)];
    if (r < CIN * S_) vsum[(size_t)b * CIN * S_ + r] = s;
    else cnt[b * S_ + (r - CIN * S_)] = s;
}

// ---------------- K2: conv + fused mean-division -> voxT f32 [b][s][64] ----------------
__global__ __launch_bounds__(256) void k_conv2(const float* __restrict__ vsum, const float* __restrict__ cnt,
                                               const float* __restrict__ w, const float* __restrict__ bias,
                                               float* __restrict__ voxT) {
    __shared__ float msl[3][CIN][256];
    __shared__ float wl[8 * 162];
    int bid = blockIdx.x;                 // b(4) x x(16) x og(8) = 512
    int b = bid >> 7;
    int x = (bid >> 3) & 15;
    int o0 = (bid & 7) * 8;
    int tid = threadIdx.x;
    for (int i = tid; i < 8 * 162; i += 256) wl[i] = w[o0 * 162 + i];
#pragma unroll
    for (int sl = 0; sl < 3; sl++) {
        int xx = x - 1 + sl;
        if (xx >= 0 && xx < 16) {
            float c = cnt[b * S_ + xx * 256 + tid];
            float invc = 1.f / fmaxf(c, 1.f);
#pragma unroll
            for (int i = 0; i < CIN; i++)
                msl[sl][i][tid] = vsum[((size_t)b * CIN + i) * S_ + xx * 256 + tid] * invc;
        } else {
#pragma unroll
            for (int i = 0; i < CIN; i++) msl[sl][i][tid] = 0.f;
        }
    }
    __syncthreads();
    int y = tid >> 4, z = tid & 15;
    float acc[8];
#pragma unroll
    for (int oj = 0; oj < 8; oj++) acc[oj] = bias[o0 + oj];
#pragma unroll
    for (int dx = 0; dx < 3; dx++) {
#pragma unroll
        for (int dy = 0; dy < 3; dy++) {
            int yy = y + dy - 1;
            if ((unsigned)yy >= 16u) continue;
#pragma unroll
            for (int dz = 0; dz < 3; dz++) {
                int zz = z + dz - 1;
                if ((unsigned)zz >= 16u) continue;
                int idx = yy * 16 + zz;
#pragma unroll
                for (int i = 0; i < CIN; i++) {
                    float m = msl[dx][i][idx];
                    int wb = i * 27 + dx * 9 + dy * 3 + dz;
#pragma unroll
                    for (int oj = 0; oj < 8; oj++) acc[oj] += wl[oj * 162 + wb] * m;
                }
            }
        }
    }
    int cell = x * 256 + tid;
    float* dst = voxT + ((size_t)b * S_ + cell) * 64 + o0;
    *(float4*)dst = make_float4(fmaxf(acc[0], 0.f), fmaxf(acc[1], 0.f), fmaxf(acc[2], 0.f), fmaxf(acc[3], 0.f));
    *(float4*)(dst + 4) = make_float4(fmaxf(acc[4], 0.f), fmaxf(acc[5], 0.f), fmaxf(acc[6], 0.f), fmaxf(acc[7], 0.f));
}

// ---------------- K3: qkv via MFMA -> qT,kT [s][64]; vT [c][t] ----------------
__global__ __launch_bounds__(256) void k_qkv4(const float* __restrict__ voxT,
                                              const float* __restrict__ wq, const float* __restrict__ wk,
                                              const float* __restrict__ wv,
                                              unsigned short* __restrict__ qT, unsigned short* __restrict__ kT,
                                              unsigned short* __restrict__ vT) {
    int bid = blockIdx.x;                 // 256: b(4) x chunk(64)
    int b = bid >> 6;
    int srow = (bid & 63) * 64 + (threadIdx.x >> 6) * 16;   // 16 rows per wave
    int lane = threadIdx.x & 63;
    int lo = lane & 15, hi = lane >> 4;

    const float* xr = voxT + ((size_t)b * S_ + srow + lo) * 64 + hi * 8;
    bf16x8 a0 = pack8b(*(const float4*)xr, *(const float4*)(xr + 4));
    bf16x8 a1 = pack8b(*(const float4*)(xr + 32), *(const float4*)(xr + 36));

#pragma unroll
    for (int m = 0; m < 3; m++) {
        const float* wp = (m == 0) ? wq : (m == 1) ? wk : wv;
#pragma unroll
        for (int oc = 0; oc < 4; oc++) {
            const float* wr = wp + (oc * 16 + lo) * 64 + hi * 8;
            bf16x8 b0 = pack8b(*(const float4*)wr, *(const float4*)(wr + 4));
            bf16x8 b1 = pack8b(*(const float4*)(wr + 32), *(const float4*)(wr + 36));
            f32x4 acc = zero4();
            acc = MFMA16(a0, b0, acc);
            acc = MFMA16(a1, b1, acc);
            if (m < 2) {
                unsigned short* dst = ((m == 0) ? qT : kT) + ((size_t)b * S_ + srow + hi * 4) * 64 + oc * 16 + lo;
#pragma unroll
                for (int j = 0; j < 4; j++) dst[(size_t)j * 64] = f2bf(acc[j]);
            } else {
                s16x4 pk;
#pragma unroll
                for (int j = 0; j < 4; j++) pk[j] = (short)f2bf(acc[j]);
                *(s16x4*)(vT + ((size_t)b * 64 + oc * 16 + lo) * S_ + srow + hi * 4) = pk;
            }
        }
    }
}

// ---------------- K4: attn — shared LDS K/V tiles, 4-way KV-split for occupancy ----------------
__global__ __launch_bounds__(256) void k_attn11(const unsigned short* __restrict__ qT,
                                                const unsigned short* __restrict__ kT,
                                                const unsigned short* __restrict__ vT,
                                                float* __restrict__ Opart, float* __restrict__ lpart) {
    __shared__ __align__(16) char Kl[8192];     // 64 t-rows x 128B, XOR-swizzled slots
    __shared__ __align__(16) char Vl[8192];     // 64 c-rows x 128B, XOR-swizzled slots
    __shared__ __align__(16) char PsB[8192];    // per-wave 2KB P buffer
    int bid = blockIdx.x;                       // 1024: b(4) x qt(64) x quarter(4)
    int b = bid >> 8;
    int qt = (bid >> 2) & 63;
    int quarter = bid & 3;
    int sq0 = qt * 64;
    int tid = threadIdx.x;
    int w = tid >> 6, lane = tid & 63;
    int lo = lane & 15, hi = lane >> 4;
    char* Ps = PsB + w * 2048;

    const unsigned short* qb = qT + ((size_t)b * S_ + sq0 + w * 16) * 64;
    bf16x8 qf0 = __builtin_bit_cast(bf16x8, *(const short8*)(qb + lo * 64 + hi * 8));
    bf16x8 qf1 = __builtin_bit_cast(bf16x8, *(const short8*)(qb + lo * 64 + hi * 8 + 32));

    f32x4 O[4];
    float l[4];
#pragma unroll
    for (int cc = 0; cc < 4; cc++) O[cc] = zero4();
#pragma unroll
    for (int j = 0; j < 4; j++) l[j] = 0.f;

    const char* kTb = (const char*)(kT + (size_t)b * S_ * 64);   // t-row = 128B
    const char* vTb = (const char*)(vT + (size_t)b * 64 * S_);   // c-row = 8192B
    int tbase = quarter * 1024;

    int swz = ((tid >> 3) & 7) << 4;
    int x0 = tid * 16;
    int vrow = tid >> 3, vslot16 = (tid & 7) * 16;

    short8 g0, g1, g2, g3;
    {
        const char* ktile = kTb + (size_t)tbase * 128;
        g0 = *(const short8*)(ktile + x0);
        g1 = *(const short8*)(ktile + x0 + 4096);
        const char* vt0 = vTb + (size_t)tbase * 2;
        g2 = *(const short8*)(vt0 + (size_t)vrow * 8192 + vslot16);
        g3 = *(const short8*)(vt0 + (size_t)(vrow + 32) * 8192 + vslot16);
    }

    for (int it = 0; it < 16; ++it) {
        __syncthreads();
        *(short8*)(Kl + (x0 ^ swz)) = g0;
        *(short8*)(Kl + ((x0 + 4096) ^ swz)) = g1;
        *(short8*)(Vl + (x0 ^ swz)) = g2;
        *(short8*)(Vl + ((x0 + 4096) ^ swz)) = g3;
        __syncthreads();
        if (it + 1 < 16) {
            int t0n = tbase + (it + 1) * 64;
            const char* ktile = kTb + (size_t)t0n * 128;
            g0 = *(const short8*)(ktile + x0);
            g1 = *(const short8*)(ktile + x0 + 4096);
            const char* vtn = vTb + (size_t)t0n * 2;
            g2 = *(const short8*)(vtn + (size_t)vrow * 8192 + vslot16);
            g3 = *(const short8*)(vtn + (size_t)(vrow + 32) * 8192 + vslot16);
        }
#pragma unroll
        for (int ct = 0; ct < 4; ct++) {
            int t = ct * 16 + lo;
            int tswz = (t & 7) << 4;
            bf16x8 kf0 = __builtin_bit_cast(bf16x8, *(const short8*)(Kl + (t * 128 + ((hi * 16) ^ tswz))));
            bf16x8 kf1 = __builtin_bit_cast(bf16x8, *(const short8*)(Kl + (t * 128 + ((64 + hi * 16) ^ tswz))));
            f32x4 z = zero4();
            z = MFMA16(qf0, kf0, z);
            f32x4 Sacc = MFMA16(qf1, kf1, z);
#pragma unroll
            for (int j = 0; j < 4; j++) {
                float p = __expf(Sacc[j] * 0.125f);
                l[j] += p;
                int r = hi * 4 + j;
                int pswz = (r & 7) << 4;
                *(unsigned short*)(Ps + ((r * 128 + t * 2) ^ pswz)) = f2bf(p);
            }
        }
        int rswz = (lo & 7) << 4;
        bf16x8 pa0 = __builtin_bit_cast(bf16x8, *(const short8*)(Ps + ((lo * 128 + hi * 16) ^ rswz)));
        bf16x8 pa1 = __builtin_bit_cast(bf16x8, *(const short8*)(Ps + ((lo * 128 + 64 + hi * 16) ^ rswz)));
#pragma unroll
        for (int cc = 0; cc < 4; cc++) {
            int c = cc * 16 + lo;
            int cswz = (c & 7) << 4;
            bf16x8 vf0 = __builtin_bit_cast(bf16x8, *(const short8*)(Vl + (c * 128 + ((hi * 16) ^ cswz))));
            bf16x8 vf1 = __builtin_bit_cast(bf16x8, *(const short8*)(Vl + (c * 128 + ((64 + hi * 16) ^ cswz))));
            O[cc] = MFMA16(pa0, vf0, O[cc]);
            O[cc] = MFMA16(pa1, vf1, O[cc]);
        }
    }

    float* ob = Opart + ((size_t)(quarter * B_ + b) * S_ + sq0 + w * 16) * 64;
#pragma unroll
    for (int cc = 0; cc < 4; cc++)
#pragma unroll
        for (int j = 0; j < 4; j++)
            ob[(size_t)(hi * 4 + j) * 64 + cc * 16 + lo] = O[cc][j];
#pragma unroll
    for (int j = 0; j < 4; j++) {
        float s = l[j];
        s += __shfl_xor(s, 1);
        s += __shfl_xor(s, 2);
        s += __shfl_xor(s, 4);
        s += __shfl_xor(s, 8);
        if (lo == 0)
            lpart[(size_t)(quarter * B_ + b) * S_ + sq0 + w * 16 + hi * 4 + j] = s;
    }
}

// ---------------- K5: combine(4 quarters) + Wo MFMA + residual + SE-mean -> xattT bf16 ----------------
__global__ __launch_bounds__(256) void k_wo_mfma(const float* __restrict__ Opart,
                                                 const float* __restrict__ lpart,
                                                 const float* __restrict__ wo,
                                                 const float* __restrict__ voxT,
                                                 unsigned short* __restrict__ xattT,
                                                 float* __restrict__ semean) {
    __shared__ float sem[64];
    int tid = threadIdx.x;
    if (tid < 64) sem[tid] = 0.f;
    __syncthreads();
    int wid = tid >> 6, lane = tid & 63;
    int lo = lane & 15, hi = lane >> 4;
    int r0 = blockIdx.x * 64 + wid * 16;               // global row (b*S + s)
    int bidx = r0 >> 12;
    int row = r0 + lo;
    const int BS = B_ * S_;

    float L = lpart[row] + lpart[BS + row] + lpart[2 * BS + row] + lpart[3 * BS + row];
    float inv = 1.f / L;
    float4 q0 = make_float4(0.f, 0.f, 0.f, 0.f), q1 = q0, q2 = q0, q3 = q0;
#pragma unroll
    for (int sp = 0; sp < 4; sp++) {
        const float* orow = Opart + ((size_t)sp * BS + row) * 64 + hi * 8;
        float4 t0 = *(const float4*)(orow);
        float4 t1 = *(const float4*)(orow + 4);
        float4 t2 = *(const float4*)(orow + 32);
        float4 t3 = *(const float4*)(orow + 36);
        q0.x += t0.x; q0.y += t0.y; q0.z += t0.z; q0.w += t0.w;
        q1.x += t1.x; q1.y += t1.y; q1.z += t1.z; q1.w += t1.w;
        q2.x += t2.x; q2.y += t2.y; q2.z += t2.z; q2.w += t2.w;
        q3.x += t3.x; q3.y += t3.y; q3.z += t3.z; q3.w += t3.w;
    }
    q0.x *= inv; q0.y *= inv; q0.z *= inv; q0.w *= inv;
    q1.x *= inv; q1.y *= inv; q1.z *= inv; q1.w *= inv;
    q2.x *= inv; q2.y *= inv; q2.z *= inv; q2.w *= inv;
    q3.x *= inv; q3.y *= inv; q3.z *= inv; q3.w *= inv;
    bf16x8 a0 = pack8b(q0, q1);
    bf16x8 a1 = pack8b(q2, q3);

    float colsum[4];
#pragma unroll
    for (int cc = 0; cc < 4; cc++) {
        int o = cc * 16 + lo;
        float4 f0 = *(const float4*)(wo + o * 64 + hi * 8);
        float4 f1 = *(const float4*)(wo + o * 64 + hi * 8 + 4);
        bf16x8 b0 = pack8b(f0, f1);
        float4 f2 = *(const float4*)(wo + o * 64 + 32 + hi * 8);
        float4 f3 = *(const float4*)(wo + o * 64 + 32 + hi * 8 + 4);
        bf16x8 b1 = pack8b(f2, f3);
        f32x4 acc = zero4();
        acc = MFMA16(a0, b0, acc);
        acc = MFMA16(a1, b1, acc);
        float cs = 0.f;
#pragma unroll
        for (int j = 0; j < 4; j++) {
            size_t idx = (size_t)(r0 + hi * 4 + j) * 64 + o;
            float xn = acc[j] + voxT[idx];
            xattT[idx] = f2bf(xn);
            cs += xn;
        }
        cs += __shfl_xor(cs, 16);
        cs += __shfl_xor(cs, 32);
        colsum[cc] = cs;
    }
    if (hi == 0) {
#pragma unroll
        for (int cc = 0; cc < 4; cc++) atomicAdd(&sem[cc * 16 + lo], colsum[cc]);
    }
    __syncthreads();
    if (tid < 64) atomicAdd(&semean[bidx * 64 + tid], sem[tid]);
}

// ---------------- K8: SE gate + devoxelize (two-pass 32-ch) + point MLP + MFMA classifier ----------------
__global__ __launch_bounds__(256) void k_point(const float* __restrict__ coords, const float* __restrict__ feats,
                                               const unsigned short* __restrict__ xt, const float* __restrict__ semean,
                                               const float* __restrict__ sw1, const float* __restrict__ sb1,
                                               const float* __restrict__ sw2, const float* __restrict__ sb2,
                                               const float* __restrict__ pw,
                                               const float* __restrict__ pb, const float* __restrict__ w1,
                                               const float* __restrict__ b1, const float* __restrict__ w2,
                                               const float* __restrict__ b2, float* __restrict__ out) {
    __shared__ unsigned short fl[256 * 64];    // 32KB fused bf16, XOR-swizzled rows
    __shared__ float pwl[64 * 6];
    __shared__ float pbl[64];
    __shared__ float b1l[128];
    __shared__ float w2l[3 * 128];
    __shared__ float b2l[3];
    __shared__ float gl[64];
    __shared__ float sml[64];
    __shared__ float hh[8];
    int tid = threadIdx.x;
    int gidx0 = blockIdx.x * 256;
    int b = gidx0 >> 15, n0 = gidx0 & (N_ - 1);
    int n = n0 + tid;
    for (int i = tid; i < 384; i += 256) { pwl[i] = pw[i]; w2l[i] = w2[i]; }
    if (tid < 128) b1l[tid] = b1[tid];
    if (tid < 64) { pbl[tid] = pb[tid]; sml[tid] = semean[b * 64 + tid] * (1.0f / S_); }
    if (tid < 3) b2l[tid] = b2[tid];
    __syncthreads();
    if (tid < 8) {
        float a = sb1[tid];
#pragma unroll
        for (int i = 0; i < 64; i++) a += sw1[tid * 64 + i] * sml[i];
        hh[tid] = fmaxf(a, 0.f);
    }
    __syncthreads();
    if (tid < 64) {
        float g = sb2[tid];
#pragma unroll
        for (int j = 0; j < 8; j++) g += sw2[tid * 8 + j] * hh[j];
        gl[tid] = 1.f / (1.f + __expf(-g));
    }
    __syncthreads();

    const float* cb = coords + (size_t)b * 3 * N_;
    float px = fminf(fmaxf(cb[n] * R_ - 0.5f, 0.f), 15.f);
    float py = fminf(fmaxf(cb[N_ + n] * R_ - 0.5f, 0.f), 15.f);
    float pz = fminf(fmaxf(cb[2 * N_ + n] * R_ - 0.5f, 0.f), 15.f);
    int x0 = (int)floorf(px); float wx = px - x0; int x1 = min(x0 + 1, 15);
    int y0 = (int)floorf(py); float wy = py - y0; int y1 = min(y0 + 1, 15);
    int z0 = (int)floorf(pz); float wz = pz - z0; int z1 = min(z0 + 1, 15);
    float fv[6];
#pragma unroll
    for (int i = 0; i < 6; i++) fv[i] = feats[((size_t)b * 6 + i) * N_ + n];

    int coff[8];
    float cwgt[8];
#pragma unroll
    for (int dx = 0; dx < 2; dx++)
#pragma unroll
        for (int dy = 0; dy < 2; dy++)
#pragma unroll
            for (int dz = 0; dz < 2; dz++) {
                int k = dx * 4 + dy * 2 + dz;
                int xi = dx ? x1 : x0, yi = dy ? y1 : y0, zi = dz ? z1 : z0;
                coff[k] = ((xi * 16 + yi) * 16 + zi) * 64;
                cwgt[k] = (dx ? wx : 1.f - wx) * (dy ? wy : 1.f - wy) * (dz ? wz : 1.f - wz);
            }

    const unsigned short* xb = xt + (size_t)b * S_ * 64;
#pragma unroll 1
    for (int h = 0; h < 2; h++) {
        float fused[32];
#pragma unroll
        for (int c = 0; c < 32; c++) fused[c] = 0.f;
#pragma unroll
        for (int k = 0; k < 8; k++) {
            const short8* g = (const short8*)(xb + coff[k] + h * 32);
            float wgt = cwgt[k];
#pragma unroll
            for (int c8 = 0; c8 < 4; c8++) {
                short8 gv = g[c8];
#pragma unroll
                for (int i = 0; i < 8; i++)
                    fused[c8 * 8 + i] += wgt * bf2f((unsigned short)gv[i]);
            }
        }
#pragma unroll
        for (int c = 0; c < 32; c++) {
            int cc = h * 32 + c;
            float pt = pbl[cc];
#pragma unroll
            for (int i = 0; i < 6; i++) pt += pwl[cc * 6 + i] * fv[i];
            pt = fmaxf(pt, 0.f);
            fused[c] = fmaxf(fused[c] * gl[cc] + pt, 0.f);
        }
#pragma unroll
        for (int ch = 0; ch < 4; ch++) {
            short8 v;
#pragma unroll
            for (int i = 0; i < 8; i++) v[i] = (short)f2bf(fused[ch * 8 + i]);
            int byte = tid * 128 + h * 64 + ch * 16;
            *(short8*)((char*)fl + (byte ^ ((tid & 7) << 4))) = v;
        }
    }
    __syncthreads();

    int wv = tid >> 6, lane = tid & 63;
    int lo = lane & 15, hi = lane >> 4;
    bf16x8 bw[16];
#pragma unroll
    for (int th = 0; th < 8; th++) {
#pragma unroll
        for (int kf = 0; kf < 2; kf++) {
            const float* wr = w1 + (th * 16 + lo) * 64 + kf * 32 + hi * 8;
            bw[th * 2 + kf] = pack8b(*(const float4*)wr, *(const float4*)(wr + 4));
        }
    }
#pragma unroll
    for (int g = 0; g < 4; g++) {
        int row = wv * 64 + g * 16 + lo;
        int swz = (row & 7) << 4;
        bf16x8 a0 = __builtin_bit_cast(bf16x8, *(const short8*)((char*)fl + ((row * 128 + hi * 16) ^ swz)));
        bf16x8 a1 = __builtin_bit_cast(bf16x8, *(const short8*)((char*)fl + ((row * 128 + 64 + hi * 16) ^ swz)));
        f32x4 acc[8];
#pragma unroll
        for (int th = 0; th < 8; th++) {
            acc[th] = zero4();
            acc[th] = MFMA16(a0, bw[th * 2], acc[th]);
            acc[th] = MFMA16(a1, bw[th * 2 + 1], acc[th]);
        }
        float s0[4] = {0.f, 0.f, 0.f, 0.f};
        float s1[4] = {0.f, 0.f, 0.f, 0.f};
        float s2[4] = {0.f, 0.f, 0.f, 0.f};
#pragma unroll
        for (int th = 0; th < 8; th++) {
            int hidx = th * 16 + lo;
            float w2o0 = w2l[hidx];
            float w2o1 = w2l[128 + hidx];
            float w2o2 = w2l[256 + hidx];
            float bias = b1l[hidx];
#pragma unroll
            for (int j = 0; j < 4; j++) {
                float hj = fmaxf(acc[th][j] + bias, 0.f);
                s0[j] += hj * w2o0;
                s1[j] += hj * w2o1;
                s2[j] += hj * w2o2;
            }
        }
#pragma unroll
        for (int j = 0; j < 4; j++) {
            s0[j] += __shfl_xor(s0[j], 1); s0[j] += __shfl_xor(s0[j], 2);
            s0[j] += __shfl_xor(s0[j], 4); s0[j] += __shfl_xor(s0[j], 8);
            s1[j] += __shfl_xor(s1[j], 1); s1[j] += __shfl_xor(s1[j], 2);
            s1[j] += __shfl_xor(s1[j], 4); s1[j] += __shfl_xor(s1[j], 8);
            s2[j] += __shfl_xor(s2[j], 1); s2[j] += __shfl_xor(s2[j], 2);
            s2[j] += __shfl_xor(s2[j], 4); s2[j] += __shfl_xor(s2[j], 8);
        }
        int nbase = n0 + wv * 64 + g * 16 + hi * 4;
        if (lo == 0) {
            float4 o4 = make_float4(s0[0] + b2l[0], s0[1] + b2l[0], s0[2] + b2l[0], s0[3] + b2l[0]);
            *(float4*)(out + ((size_t)b * 3 + 0) * N_ + nbase) = o4;
        } else if (lo == 1) {
            float4 o4 = make_float4(s1[0] + b2l[1], s1[1] + b2l[1], s1[2] + b2l[1], s1[3] + b2l[1]);
            *(float4*)(out + ((size_t)b * 3 + 1) * N_ + nbase) = o4;
        } else if (lo == 2) {
            float4 o4 = make_float4(s2[0] + b2l[2], s2[1] + b2l[2], s2[2] + b2l[2], s2[3] + b2l[2]);
            *(float4*)(out + ((size_t)b * 3 + 2) * N_ + nbase) = o4;
        }
    }
}

extern "C" void kernel_launch(void* const* d_in, const int* in_sizes, int n_in,
                              void* d_out, int out_size, void* d_ws, size_t ws_size,
                              hipStream_t stream) {
    const float* coords  = (const float*)d_in[0];
    const float* feats   = (const float*)d_in[1];
    const float* conv_w  = (const float*)d_in[2];
    const float* conv_b  = (const float*)d_in[3];
    const float* wq      = (const float*)d_in[4];
    const float* wk      = (const float*)d_in[5];
    const float* wv      = (const float*)d_in[6];
    const float* wo      = (const float*)d_in[7];
    const float* se_w1   = (const float*)d_in[8];
    const float* se_b1   = (const float*)d_in[9];
    const float* se_w2   = (const float*)d_in[10];
    const float* se_b2   = (const float*)d_in[11];
    const float* point_w = (const float*)d_in[12];
    const float* point_b = (const float*)d_in[13];
    const float* cls_w1  = (const float*)d_in[14];
    const float* cls_b1  = (const float*)d_in[15];
    const float* cls_w2  = (const float*)d_in[16];
    const float* cls_b2  = (const float*)d_in[17];

    float* ws = (float*)d_ws;
    float* vsum   = ws;                        // 98304
    float* cnt    = ws + 98304;                // 16384
    float* semean = ws + 114688;               // 256
    float* vox    = ws + 115200;               // region reused as xattT (bf16)
    float* voxT   = vox + 1048576;             // f32 [b][s][64]: conv2 -> qkv4 + wo residual
    unsigned short* qT = (unsigned short*)(voxT + 1048576);
    unsigned short* kT = qT + 1048576;
    unsigned short* vT = kT + 1048576;
    float* Opart  = (float*)(vT + 1048576);    // 4 quarters x 16384 x 64 = 4194304 f32 (vox partials reuse)
    float* lpart  = Opart + 4194304;           // 65536
    unsigned short* xattT = (unsigned short*)vox;   // bf16 [b][s][64]

    hipMemsetAsync(semean, 0, 256 * sizeof(float), stream);   // semean only (atomic accum)
    k_vox_part<<<64, 1024, 0, stream>>>(coords, feats, Opart);
    k_vox_reduce<<<448, 256, 0, stream>>>(Opart, vsum, cnt);
    k_conv2<<<512, 256, 0, stream>>>(vsum, cnt, conv_w, conv_b, voxT);
    k_qkv4<<<256, 256, 0, stream>>>(voxT, wq, wk, wv, qT, kT, vT);
    k_attn11<<<1024, 256, 0, stream>>>(qT, kT, vT, Opart, lpart);
    k_wo_mfma<<<256, 256, 0, stream>>>(Opart, lpart, wo, voxT, xattT, semean);
    k_point<<<512, 256, 0, stream>>>(coords, feats, xattT, semean,
                                     se_w1, se_b1, se_w2, se_b2, point_w, point_b,
                                     cls_w1, cls_b1, cls_w2, cls_b2, (float*)d_out);
}

// Round 23
// 150.974 us; speedup vs baseline: 1.1406x; 1.0047x over previous
//
#include <hip/hip_runtime.h>
#include <hip/hip_bf16.h>
#include <math.h>

#define B_ 4
#define N_ 32768
#define CIN 6
#define C_ 64
#define R_ 16
#define S_ 4096

typedef __attribute__((ext_vector_type(8))) __bf16 bf16x8;
typedef __attribute__((ext_vector_type(8))) short short8;
typedef __attribute__((ext_vector_type(4))) short s16x4;
typedef __attribute__((ext_vector_type(4))) float f32x4;

#define MFMA16(a, b, c) __builtin_amdgcn_mfma_f32_16x16x32_bf16((a), (b), (c), 0, 0, 0)

__device__ inline f32x4 zero4() {
    f32x4 z;
    z[0] = 0.f; z[1] = 0.f; z[2] = 0.f; z[3] = 0.f;
    return z;
}

__device__ inline unsigned short f2bf(float f) {
    unsigned u = __builtin_bit_cast(unsigned, f);
    u += 0x7fffu + ((u >> 16) & 1u);          // RNE
    return (unsigned short)(u >> 16);
}

__device__ inline float bf2f(unsigned short s) {
    unsigned u = ((unsigned)s) << 16;
    return __builtin_bit_cast(float, u);
}

__device__ inline short8 pack8(float4 a, float4 b) {
    short8 r;
    r[0] = (short)f2bf(a.x); r[1] = (short)f2bf(a.y); r[2] = (short)f2bf(a.z); r[3] = (short)f2bf(a.w);
    r[4] = (short)f2bf(b.x); r[5] = (short)f2bf(b.y); r[6] = (short)f2bf(b.z); r[7] = (short)f2bf(b.w);
    return r;
}

__device__ inline bf16x8 pack8b(float4 a, float4 b) {
    return __builtin_bit_cast(bf16x8, pack8(a, b));
}

// ---------------- K1a: per-block partial LDS histograms (no global atomics) ----------------
__global__ __launch_bounds__(1024) void k_vox_part(const float* __restrict__ coords,
                                                   const float* __restrict__ feats,
                                                   float* __restrict__ part) {
    __shared__ float hist[7 * S_];             // 114688 B
    int bid = blockIdx.x;                      // 64: b(4) x p(16)
    int b = bid >> 4, p = bid & 15;
    int tid = threadIdx.x;
    for (int i = tid; i < 7 * S_; i += 1024) hist[i] = 0.f;
    __syncthreads();
    const float* cb = coords + (size_t)b * 3 * N_;
    const float* fb = feats + (size_t)b * CIN * N_;
#pragma unroll
    for (int it = 0; it < 2; ++it) {
        int n = p * 2048 + it * 1024 + tid;
        float x = cb[n], y = cb[N_ + n], z = cb[2 * N_ + n];
        int vx = min(max((int)floorf(x * R_), 0), R_ - 1);
        int vy = min(max((int)floorf(y * R_), 0), R_ - 1);
        int vz = min(max((int)floorf(z * R_), 0), R_ - 1);
        int cell = (vx * R_ + vy) * R_ + vz;
#pragma unroll
        for (int f = 0; f < CIN; f++) atomicAdd(&hist[f * S_ + cell], fb[f * N_ + n]);
        atomicAdd(&hist[6 * S_ + cell], 1.0f);
    }
    __syncthreads();
    float* dst = part + (size_t)bid * (7 * S_);
    for (int i = tid; i < 7 * S_; i += 1024) dst[i] = hist[i];
}

// ---------------- K1b: fold 16 partials -> vsum, cnt ----------------
__global__ __launch_bounds__(256) void k_vox_reduce(const float* __restrict__ part,
                                                    float* __restrict__ vsum, float* __restrict__ cnt) {
    int idx = blockIdx.x * 256 + threadIdx.x;  // 4 * 28672 = 114688 threads
    int b = idx / (7 * S_);
    int r = idx - b * (7 * S_);
    const float* pb = part + (size_t)b * 16 * (7 * S_) + r;
    float s = 0.f;
#pragma unroll
    for (int p = 0; p < 16; p++) s += pb[(size_t)p * (7 * S_)];
    if (r < CIN * S_) vsum[(size_t)b * CIN * S_ + r] = s;
    else cnt[b * S_ + (r - CIN * S_)] = s;
}

// ---------------- K2: conv + fused mean-division -> voxT f32 [b][s][64] ----------------
__global__ __launch_bounds__(256) void k_conv2(const float* __restrict__ vsum, const float* __restrict__ cnt,
                                               const float* __restrict__ w, const float* __restrict__ bias,
                                               float* __restrict__ voxT) {
    __shared__ float msl[3][CIN][256];
    __shared__ float wl[8 * 162];
    int bid = blockIdx.x;                 // b(4) x x(16) x og(8) = 512
    int b = bid >> 7;
    int x = (bid >> 3) & 15;
    int o0 = (bid & 7) * 8;
    int tid = threadIdx.x;
    for (int i = tid; i < 8 * 162; i += 256) wl[i] = w[o0 * 162 + i];
#pragma unroll
    for (int sl = 0; sl < 3; sl++) {
        int xx = x - 1 + sl;
        if (xx >= 0 && xx < 16) {
            float c = cnt[b * S_ + xx * 256 + tid];
            float invc = 1.f / fmaxf(c, 1.f);
#pragma unroll
            for (int i = 0; i < CIN; i++)
                msl[sl][i][tid] = vsum[((size_t)b * CIN + i) * S_ + xx * 256 + tid] * invc;
        } else {
#pragma unroll
            for (int i = 0; i < CIN; i++) msl[sl][i][tid] = 0.f;
        }
    }
    __syncthreads();
    int y = tid >> 4, z = tid & 15;
    float acc[8];
#pragma unroll
    for (int oj = 0; oj < 8; oj++) acc[oj] = bias[o0 + oj];
#pragma unroll
    for (int dx = 0; dx < 3; dx++) {
#pragma unroll
        for (int dy = 0; dy < 3; dy++) {
            int yy = y + dy - 1;
            if ((unsigned)yy >= 16u) continue;
#pragma unroll
            for (int dz = 0; dz < 3; dz++) {
                int zz = z + dz - 1;
                if ((unsigned)zz >= 16u) continue;
                int idx = yy * 16 + zz;
#pragma unroll
                for (int i = 0; i < CIN; i++) {
                    float m = msl[dx][i][idx];
                    int wb = i * 27 + dx * 9 + dy * 3 + dz;
#pragma unroll
                    for (int oj = 0; oj < 8; oj++) acc[oj] += wl[oj * 162 + wb] * m;
                }
            }
        }
    }
    int cell = x * 256 + tid;
    float* dst = voxT + ((size_t)b * S_ + cell) * 64 + o0;
    *(float4*)dst = make_float4(fmaxf(acc[0], 0.f), fmaxf(acc[1], 0.f), fmaxf(acc[2], 0.f), fmaxf(acc[3], 0.f));
    *(float4*)(dst + 4) = make_float4(fmaxf(acc[4], 0.f), fmaxf(acc[5], 0.f), fmaxf(acc[6], 0.f), fmaxf(acc[7], 0.f));
}

// ---------------- K3: qkv via MFMA -> qT,kT [s][64]; vT [c][t] ----------------
__global__ __launch_bounds__(256) void k_qkv4(const float* __restrict__ voxT,
                                              const float* __restrict__ wq, const float* __restrict__ wk,
                                              const float* __restrict__ wv,
                                              unsigned short* __restrict__ qT, unsigned short* __restrict__ kT,
                                              unsigned short* __restrict__ vT) {
    int bid = blockIdx.x;                 // 256: b(4) x chunk(64)
    int b = bid >> 6;
    int srow = (bid & 63) * 64 + (threadIdx.x >> 6) * 16;   // 16 rows per wave
    int lane = threadIdx.x & 63;
    int lo = lane & 15, hi = lane >> 4;

    const float* xr = voxT + ((size_t)b * S_ + srow + lo) * 64 + hi * 8;
    bf16x8 a0 = pack8b(*(const float4*)xr, *(const float4*)(xr + 4));
    bf16x8 a1 = pack8b(*(const float4*)(xr + 32), *(const float4*)(xr + 36));

#pragma unroll
    for (int m = 0; m < 3; m++) {
        const float* wp = (m == 0) ? wq : (m == 1) ? wk : wv;
#pragma unroll
        for (int oc = 0; oc < 4; oc++) {
            const float* wr = wp + (oc * 16 + lo) * 64 + hi * 8;
            bf16x8 b0 = pack8b(*(const float4*)wr, *(const float4*)(wr + 4));
            bf16x8 b1 = pack8b(*(const float4*)(wr + 32), *(const float4*)(wr + 36));
            f32x4 acc = zero4();
            acc = MFMA16(a0, b0, acc);
            acc = MFMA16(a1, b1, acc);
            if (m < 2) {
                unsigned short* dst = ((m == 0) ? qT : kT) + ((size_t)b * S_ + srow + hi * 4) * 64 + oc * 16 + lo;
#pragma unroll
                for (int j = 0; j < 4; j++) dst[(size_t)j * 64] = f2bf(acc[j]);
            } else {
                s16x4 pk;
#pragma unroll
                for (int j = 0; j < 4; j++) pk[j] = (short)f2bf(acc[j]);
                *(s16x4*)(vT + ((size_t)b * 64 + oc * 16 + lo) * S_ + srow + hi * 4) = pk;
            }
        }
    }
}

// ---------------- K4: attn — double-buffered LDS K/V tiles, ONE barrier per iteration ----------------
__global__ __launch_bounds__(256) void k_attn12(const unsigned short* __restrict__ qT,
                                                const unsigned short* __restrict__ kT,
                                                const unsigned short* __restrict__ vT,
                                                float* __restrict__ Opart, float* __restrict__ lpart) {
    __shared__ __align__(16) char Kl[2][8192];   // ping-pong K tiles
    __shared__ __align__(16) char Vl[2][8192];   // ping-pong V tiles
    __shared__ __align__(16) char PsB[8192];     // per-wave 2KB P buffer
    int bid = blockIdx.x;                        // 1024: b(4) x qt(64) x quarter(4)
    int b = bid >> 8;
    int qt = (bid >> 2) & 63;
    int quarter = bid & 3;
    int sq0 = qt * 64;
    int tid = threadIdx.x;
    int w = tid >> 6, lane = tid & 63;
    int lo = lane & 15, hi = lane >> 4;
    char* Ps = PsB + w * 2048;

    const unsigned short* qb = qT + ((size_t)b * S_ + sq0 + w * 16) * 64;
    bf16x8 qf0 = __builtin_bit_cast(bf16x8, *(const short8*)(qb + lo * 64 + hi * 8));
    bf16x8 qf1 = __builtin_bit_cast(bf16x8, *(const short8*)(qb + lo * 64 + hi * 8 + 32));

    f32x4 O[4];
    float l[4];
#pragma unroll
    for (int cc = 0; cc < 4; cc++) O[cc] = zero4();
#pragma unroll
    for (int j = 0; j < 4; j++) l[j] = 0.f;

    const char* kTb = (const char*)(kT + (size_t)b * S_ * 64);   // t-row = 128B
    const char* vTb = (const char*)(vT + (size_t)b * 64 * S_);   // c-row = 8192B
    int tbase = quarter * 1024;

    int swz = ((tid >> 3) & 7) << 4;
    int x0 = tid * 16;
    int vrow = tid >> 3, vslot16 = (tid & 7) * 16;

    short8 g0, g1, g2, g3;
    // load tile 0
    {
        const char* ktile = kTb + (size_t)tbase * 128;
        g0 = *(const short8*)(ktile + x0);
        g1 = *(const short8*)(ktile + x0 + 4096);
        const char* vt0 = vTb + (size_t)tbase * 2;
        g2 = *(const short8*)(vt0 + (size_t)vrow * 8192 + vslot16);
        g3 = *(const short8*)(vt0 + (size_t)(vrow + 32) * 8192 + vslot16);
    }
    // write tile 0 into buf0
    *(short8*)(Kl[0] + (x0 ^ swz)) = g0;
    *(short8*)(Kl[0] + ((x0 + 4096) ^ swz)) = g1;
    *(short8*)(Vl[0] + (x0 ^ swz)) = g2;
    *(short8*)(Vl[0] + ((x0 + 4096) ^ swz)) = g3;
    // issue loads for tile 1
    {
        int t1 = tbase + 64;
        const char* ktile = kTb + (size_t)t1 * 128;
        g0 = *(const short8*)(ktile + x0);
        g1 = *(const short8*)(ktile + x0 + 4096);
        const char* vt1 = vTb + (size_t)t1 * 2;
        g2 = *(const short8*)(vt1 + (size_t)vrow * 8192 + vslot16);
        g3 = *(const short8*)(vt1 + (size_t)(vrow + 32) * 8192 + vslot16);
    }
    __syncthreads();                             // buf0 visible

    for (int it = 0; it < 16; ++it) {
        const char* Kc = Kl[it & 1];
        const char* Vc = Vl[it & 1];
        // ---- QK^T + fixed-max softmax from current buffer ----
#pragma unroll
        for (int ct = 0; ct < 4; ct++) {
            int t = ct * 16 + lo;
            int tswz = (t & 7) << 4;
            bf16x8 kf0 = __builtin_bit_cast(bf16x8, *(const short8*)(Kc + (t * 128 + ((hi * 16) ^ tswz))));
            bf16x8 kf1 = __builtin_bit_cast(bf16x8, *(const short8*)(Kc + (t * 128 + ((64 + hi * 16) ^ tswz))));
            f32x4 z = zero4();
            z = MFMA16(qf0, kf0, z);
            f32x4 Sacc = MFMA16(qf1, kf1, z);
#pragma unroll
            for (int j = 0; j < 4; j++) {
                float p = __expf(Sacc[j] * 0.125f);
                l[j] += p;
                int r = hi * 4 + j;
                int pswz = (r & 7) << 4;
                *(unsigned short*)(Ps + ((r * 128 + t * 2) ^ pswz)) = f2bf(p);
            }
        }
        int rswz = (lo & 7) << 4;
        bf16x8 pa0 = __builtin_bit_cast(bf16x8, *(const short8*)(Ps + ((lo * 128 + hi * 16) ^ rswz)));
        bf16x8 pa1 = __builtin_bit_cast(bf16x8, *(const short8*)(Ps + ((lo * 128 + 64 + hi * 16) ^ rswz)));
#pragma unroll
        for (int cc = 0; cc < 4; cc++) {
            int c = cc * 16 + lo;
            int cswz = (c & 7) << 4;
            bf16x8 vf0 = __builtin_bit_cast(bf16x8, *(const short8*)(Vc + (c * 128 + ((hi * 16) ^ cswz))));
            bf16x8 vf1 = __builtin_bit_cast(bf16x8, *(const short8*)(Vc + (c * 128 + ((64 + hi * 16) ^ cswz))));
            O[cc] = MFMA16(pa0, vf0, O[cc]);
            O[cc] = MFMA16(pa1, vf1, O[cc]);
        }
        // ---- write tile it+1 into other buffer; issue loads for tile it+2 ----
        if (it + 1 < 16) {
            char* Kn = Kl[(it + 1) & 1];
            char* Vn = Vl[(it + 1) & 1];
            *(short8*)(Kn + (x0 ^ swz)) = g0;
            *(short8*)(Kn + ((x0 + 4096) ^ swz)) = g1;
            *(short8*)(Vn + (x0 ^ swz)) = g2;
            *(short8*)(Vn + ((x0 + 4096) ^ swz)) = g3;
            if (it + 2 < 16) {
                int t2 = tbase + (it + 2) * 64;
                const char* ktile = kTb + (size_t)t2 * 128;
                g0 = *(const short8*)(ktile + x0);
                g1 = *(const short8*)(ktile + x0 + 4096);
                const char* vt2 = vTb + (size_t)t2 * 2;
                g2 = *(const short8*)(vt2 + (size_t)vrow * 8192 + vslot16);
                g3 = *(const short8*)(vt2 + (size_t)(vrow + 32) * 8192 + vslot16);
            }
        }
        __syncthreads();                         // publish buf[(it+1)&1]
    }

    float* ob = Opart + ((size_t)(quarter * B_ + b) * S_ + sq0 + w * 16) * 64;
#pragma unroll
    for (int cc = 0; cc < 4; cc++)
#pragma unroll
        for (int j = 0; j < 4; j++)
            ob[(size_t)(hi * 4 + j) * 64 + cc * 16 + lo] = O[cc][j];
#pragma unroll
    for (int j = 0; j < 4; j++) {
        float s = l[j];
        s += __shfl_xor(s, 1);
        s += __shfl_xor(s, 2);
        s += __shfl_xor(s, 4);
        s += __shfl_xor(s, 8);
        if (lo == 0)
            lpart[(size_t)(quarter * B_ + b) * S_ + sq0 + w * 16 + hi * 4 + j] = s;
    }
}

// ---------------- K5: combine(4 quarters) + Wo MFMA + residual + SE-mean -> xattT bf16 ----------------
__global__ __launch_bounds__(256) void k_wo_mfma(const float* __restrict__ Opart,
                                                 const float* __restrict__ lpart,
                                                 const float* __restrict__ wo,
                                                 const float* __restrict__ voxT,
                                                 unsigned short* __restrict__ xattT,
                                                 float* __restrict__ semean) {
    __shared__ float sem[64];
    int tid = threadIdx.x;
    if (tid < 64) sem[tid] = 0.f;
    __syncthreads();
    int wid = tid >> 6, lane = tid & 63;
    int lo = lane & 15, hi = lane >> 4;
    int r0 = blockIdx.x * 64 + wid * 16;               // global row (b*S + s)
    int bidx = r0 >> 12;
    int row = r0 + lo;
    const int BS = B_ * S_;

    float L = lpart[row] + lpart[BS + row] + lpart[2 * BS + row] + lpart[3 * BS + row];
    float inv = 1.f / L;
    float4 q0 = make_float4(0.f, 0.f, 0.f, 0.f), q1 = q0, q2 = q0, q3 = q0;
#pragma unroll
    for (int sp = 0; sp < 4; sp++) {
        const float* orow = Opart + ((size_t)sp * BS + row) * 64 + hi * 8;
        float4 t0 = *(const float4*)(orow);
        float4 t1 = *(const float4*)(orow + 4);
        float4 t2 = *(const float4*)(orow + 32);
        float4 t3 = *(const float4*)(orow + 36);
        q0.x += t0.x; q0.y += t0.y; q0.z += t0.z; q0.w += t0.w;
        q1.x += t1.x; q1.y += t1.y; q1.z += t1.z; q1.w += t1.w;
        q2.x += t2.x; q2.y += t2.y; q2.z += t2.z; q2.w += t2.w;
        q3.x += t3.x; q3.y += t3.y; q3.z += t3.z; q3.w += t3.w;
    }
    q0.x *= inv; q0.y *= inv; q0.z *= inv; q0.w *= inv;
    q1.x *= inv; q1.y *= inv; q1.z *= inv; q1.w *= inv;
    q2.x *= inv; q2.y *= inv; q2.z *= inv; q2.w *= inv;
    q3.x *= inv; q3.y *= inv; q3.z *= inv; q3.w *= inv;
    bf16x8 a0 = pack8b(q0, q1);
    bf16x8 a1 = pack8b(q2, q3);

    float colsum[4];
#pragma unroll
    for (int cc = 0; cc < 4; cc++) {
        int o = cc * 16 + lo;
        float4 f0 = *(const float4*)(wo + o * 64 + hi * 8);
        float4 f1 = *(const float4*)(wo + o * 64 + hi * 8 + 4);
        bf16x8 b0 = pack8b(f0, f1);
        float4 f2 = *(const float4*)(wo + o * 64 + 32 + hi * 8);
        float4 f3 = *(const float4*)(wo + o * 64 + 32 + hi * 8 + 4);
        bf16x8 b1 = pack8b(f2, f3);
        f32x4 acc = zero4();
        acc = MFMA16(a0, b0, acc);
        acc = MFMA16(a1, b1, acc);
        float cs = 0.f;
#pragma unroll
        for (int j = 0; j < 4; j++) {
            size_t idx = (size_t)(r0 + hi * 4 + j) * 64 + o;
            float xn = acc[j] + voxT[idx];
            xattT[idx] = f2bf(xn);
            cs += xn;
        }
        cs += __shfl_xor(cs, 16);
        cs += __shfl_xor(cs, 32);
        colsum[cc] = cs;
    }
    if (hi == 0) {
#pragma unroll
        for (int cc = 0; cc < 4; cc++) atomicAdd(&sem[cc * 16 + lo], colsum[cc]);
    }
    __syncthreads();
    if (tid < 64) atomicAdd(&semean[bidx * 64 + tid], sem[tid]);
}

// ---------------- K8: SE gate + devoxelize (two-pass 32-ch) + point MLP + MFMA classifier ----------------
__global__ __launch_bounds__(256) void k_point(const float* __restrict__ coords, const float* __restrict__ feats,
                                               const unsigned short* __restrict__ xt, const float* __restrict__ semean,
                                               const float* __restrict__ sw1, const float* __restrict__ sb1,
                                               const float* __restrict__ sw2, const float* __restrict__ sb2,
                                               const float* __restrict__ pw,
                                               const float* __restrict__ pb, const float* __restrict__ w1,
                                               const float* __restrict__ b1, const float* __restrict__ w2,
                                               const float* __restrict__ b2, float* __restrict__ out) {
    __shared__ unsigned short fl[256 * 64];    // 32KB fused bf16, XOR-swizzled rows
    __shared__ float pwl[64 * 6];
    __shared__ float pbl[64];
    __shared__ float b1l[128];
    __shared__ float w2l[3 * 128];
    __shared__ float b2l[3];
    __shared__ float gl[64];
    __shared__ float sml[64];
    __shared__ float hh[8];
    int tid = threadIdx.x;
    int gidx0 = blockIdx.x * 256;
    int b = gidx0 >> 15, n0 = gidx0 & (N_ - 1);
    int n = n0 + tid;
    for (int i = tid; i < 384; i += 256) { pwl[i] = pw[i]; w2l[i] = w2[i]; }
    if (tid < 128) b1l[tid] = b1[tid];
    if (tid < 64) { pbl[tid] = pb[tid]; sml[tid] = semean[b * 64 + tid] * (1.0f / S_); }
    if (tid < 3) b2l[tid] = b2[tid];
    __syncthreads();
    if (tid < 8) {
        float a = sb1[tid];
#pragma unroll
        for (int i = 0; i < 64; i++) a += sw1[tid * 64 + i] * sml[i];
        hh[tid] = fmaxf(a, 0.f);
    }
    __syncthreads();
    if (tid < 64) {
        float g = sb2[tid];
#pragma unroll
        for (int j = 0; j < 8; j++) g += sw2[tid * 8 + j] * hh[j];
        gl[tid] = 1.f / (1.f + __expf(-g));
    }
    __syncthreads();

    const float* cb = coords + (size_t)b * 3 * N_;
    float px = fminf(fmaxf(cb[n] * R_ - 0.5f, 0.f), 15.f);
    float py = fminf(fmaxf(cb[N_ + n] * R_ - 0.5f, 0.f), 15.f);
    float pz = fminf(fmaxf(cb[2 * N_ + n] * R_ - 0.5f, 0.f), 15.f);
    int x0 = (int)floorf(px); float wx = px - x0; int x1 = min(x0 + 1, 15);
    int y0 = (int)floorf(py); float wy = py - y0; int y1 = min(y0 + 1, 15);
    int z0 = (int)floorf(pz); float wz = pz - z0; int z1 = min(z0 + 1, 15);
    float fv[6];
#pragma unroll
    for (int i = 0; i < 6; i++) fv[i] = feats[((size_t)b * 6 + i) * N_ + n];

    int coff[8];
    float cwgt[8];
#pragma unroll
    for (int dx = 0; dx < 2; dx++)
#pragma unroll
        for (int dy = 0; dy < 2; dy++)
#pragma unroll
            for (int dz = 0; dz < 2; dz++) {
                int k = dx * 4 + dy * 2 + dz;
                int xi = dx ? x1 : x0, yi = dy ? y1 : y0, zi = dz ? z1 : z0;
                coff[k] = ((xi * 16 + yi) * 16 + zi) * 64;
                cwgt[k] = (dx ? wx : 1.f - wx) * (dy ? wy : 1.f - wy) * (dz ? wz : 1.f - wz);
            }

    const unsigned short* xb = xt + (size_t)b * S_ * 64;
#pragma unroll 1
    for (int h = 0; h < 2; h++) {
        float fused[32];
#pragma unroll
        for (int c = 0; c < 32; c++) fused[c] = 0.f;
#pragma unroll
        for (int k = 0; k < 8; k++) {
            const short8* g = (const short8*)(xb + coff[k] + h * 32);
            float wgt = cwgt[k];
#pragma unroll
            for (int c8 = 0; c8 < 4; c8++) {
                short8 gv = g[c8];
#pragma unroll
                for (int i = 0; i < 8; i++)
                    fused[c8 * 8 + i] += wgt * bf2f((unsigned short)gv[i]);
            }
        }
#pragma unroll
        for (int c = 0; c < 32; c++) {
            int cc = h * 32 + c;
            float pt = pbl[cc];
#pragma unroll
            for (int i = 0; i < 6; i++) pt += pwl[cc * 6 + i] * fv[i];
            pt = fmaxf(pt, 0.f);
            fused[c] = fmaxf(fused[c] * gl[cc] + pt, 0.f);
        }
#pragma unroll
        for (int ch = 0; ch < 4; ch++) {
            short8 v;
#pragma unroll
            for (int i = 0; i < 8; i++) v[i] = (short)f2bf(fused[ch * 8 + i]);
            int byte = tid * 128 + h * 64 + ch * 16;
            *(short8*)((char*)fl + (byte ^ ((tid & 7) << 4))) = v;
        }
    }
    __syncthreads();

    int wv = tid >> 6, lane = tid & 63;
    int lo = lane & 15, hi = lane >> 4;
    bf16x8 bw[16];
#pragma unroll
    for (int th = 0; th < 8; th++) {
#pragma unroll
        for (int kf = 0; kf < 2; kf++) {
            const float* wr = w1 + (th * 16 + lo) * 64 + kf * 32 + hi * 8;
            bw[th * 2 + kf] = pack8b(*(const float4*)wr, *(const float4*)(wr + 4));
        }
    }
#pragma unroll
    for (int g = 0; g < 4; g++) {
        int row = wv * 64 + g * 16 + lo;
        int swz = (row & 7) << 4;
        bf16x8 a0 = __builtin_bit_cast(bf16x8, *(const short8*)((char*)fl + ((row * 128 + hi * 16) ^ swz)));
        bf16x8 a1 = __builtin_bit_cast(bf16x8, *(const short8*)((char*)fl + ((row * 128 + 64 + hi * 16) ^ swz)));
        f32x4 acc[8];
#pragma unroll
        for (int th = 0; th < 8; th++) {
            acc[th] = zero4();
            acc[th] = MFMA16(a0, bw[th * 2], acc[th]);
            acc[th] = MFMA16(a1, bw[th * 2 + 1], acc[th]);
        }
        float s0[4] = {0.f, 0.f, 0.f, 0.f};
        float s1[4] = {0.f, 0.f, 0.f, 0.f};
        float s2[4] = {0.f, 0.f, 0.f, 0.f};
#pragma unroll
        for (int th = 0; th < 8; th++) {
            int hidx = th * 16 + lo;
            float w2o0 = w2l[hidx];
            float w2o1 = w2l[128 + hidx];
            float w2o2 = w2l[256 + hidx];
            float bias = b1l[hidx];
#pragma unroll
            for (int j = 0; j < 4; j++) {
                float hj = fmaxf(acc[th][j] + bias, 0.f);
                s0[j] += hj * w2o0;
                s1[j] += hj * w2o1;
                s2[j] += hj * w2o2;
            }
        }
#pragma unroll
        for (int j = 0; j < 4; j++) {
            s0[j] += __shfl_xor(s0[j], 1); s0[j] += __shfl_xor(s0[j], 2);
            s0[j] += __shfl_xor(s0[j], 4); s0[j] += __shfl_xor(s0[j], 8);
            s1[j] += __shfl_xor(s1[j], 1); s1[j] += __shfl_xor(s1[j], 2);
            s1[j] += __shfl_xor(s1[j], 4); s1[j] += __shfl_xor(s1[j], 8);
            s2[j] += __shfl_xor(s2[j], 1); s2[j] += __shfl_xor(s2[j], 2);
            s2[j] += __shfl_xor(s2[j], 4); s2[j] += __shfl_xor(s2[j], 8);
        }
        int nbase = n0 + wv * 64 + g * 16 + hi * 4;
        if (lo == 0) {
            float4 o4 = make_float4(s0[0] + b2l[0], s0[1] + b2l[0], s0[2] + b2l[0], s0[3] + b2l[0]);
            *(float4*)(out + ((size_t)b * 3 + 0) * N_ + nbase) = o4;
        } else if (lo == 1) {
            float4 o4 = make_float4(s1[0] + b2l[1], s1[1] + b2l[1], s1[2] + b2l[1], s1[3] + b2l[1]);
            *(float4*)(out + ((size_t)b * 3 + 1) * N_ + nbase) = o4;
        } else if (lo == 2) {
            float4 o4 = make_float4(s2[0] + b2l[2], s2[1] + b2l[2], s2[2] + b2l[2], s2[3] + b2l[2]);
            *(float4*)(out + ((size_t)b * 3 + 2) * N_ + nbase) = o4;
        }
    }
}

extern "C" void kernel_launch(void* const* d_in, const int* in_sizes, int n_in,
                              void* d_out, int out_size, void* d_ws, size_t ws_size,
                              hipStream_t stream) {
    const float* coords  = (const float*)d_in[0];
    const float* feats   = (const float*)d_in[1];
    const float* conv_w  = (const float*)d_in[2];
    const float* conv_b  = (const float*)d_in[3];
    const float* wq      = (const float*)d_in[4];
    const float* wk      = (const float*)d_in[5];
    const float* wv      = (const float*)d_in[6];
    const float* wo      = (const float*)d_in[7];
    const float* se_w1   = (const float*)d_in[8];
    const float* se_b1   = (const float*)d_in[9];
    const float* se_w2   = (const float*)d_in[10];
    const float* se_b2   = (const float*)d_in[11];
    const float* point_w = (const float*)d_in[12];
    const float* point_b = (const float*)d_in[13];
    const float* cls_w1  = (const float*)d_in[14];
    const float* cls_b1  = (const float*)d_in[15];
    const float* cls_w2  = (const float*)d_in[16];
    const float* cls_b2  = (const float*)d_in[17];

    float* ws = (float*)d_ws;
    float* vsum   = ws;                        // 98304
    float* cnt    = ws + 98304;                // 16384
    float* semean = ws + 114688;               // 256
    float* vox    = ws + 115200;               // region reused as xattT (bf16)
    float* voxT   = vox + 1048576;             // f32 [b][s][64]: conv2 -> qkv4 + wo residual
    unsigned short* qT = (unsigned short*)(voxT + 1048576);
    unsigned short* kT = qT + 1048576;
    unsigned short* vT = kT + 1048576;
    float* Opart  = (float*)(vT + 1048576);    // 4 quarters x 16384 x 64 (vox partials reuse)
    float* lpart  = Opart + 4194304;           // 65536
    unsigned short* xattT = (unsigned short*)vox;   // bf16 [b][s][64]

    hipMemsetAsync(semean, 0, 256 * sizeof(float), stream);   // semean only (atomic accum)
    k_vox_part<<<64, 1024, 0, stream>>>(coords, feats, Opart);
    k_vox_reduce<<<448, 256, 0, stream>>>(Opart, vsum, cnt);
    k_conv2<<<512, 256, 0, stream>>>(vsum, cnt, conv_w, conv_b, voxT);
    k_qkv4<<<256, 256, 0, stream>>>(voxT, wq, wk, wv, qT, kT, vT);
    k_attn12<<<1024, 256, 0, stream>>>(qT, kT, vT, Opart, lpart);
    k_wo_mfma<<<256, 256, 0, stream>>>(Opart, lpart, wo, voxT, xattT, semean);
    k_point<<<512, 256, 0, stream>>>(coords, feats, xattT, semean,
                                     se_w1, se_b1, se_w2, se_b2, point_w, point_b,
                                     cls_w1, cls_b1, cls_w2, cls_b2, (float*)d_out);
}